// Round 1
// 160.939 us; speedup vs baseline: 1.0414x; 1.0414x over previous
//
#include <hip/hip_runtime.h>
#include <hip/hip_bf16.h>
#include <math.h>

// N=10000, E=160000, DIN=DOUT=256. edge_index is int32 (verified R4/R5).
#define D 256
#define CAP 128           // per-node edge slots; max degree ~45 for this graph
#define NEG_SLOPE 0.2f
#define BN_EPS 1e-5f

typedef __attribute__((ext_vector_type(8))) short bf16x8;
typedef __attribute__((ext_vector_type(8))) unsigned short ushort8;
typedef __attribute__((ext_vector_type(4))) float f32x4;

__device__ inline unsigned short f2bf(float f) {
    union { float f; unsigned u; } v; v.f = f;
    unsigned u = v.u;
    unsigned r = u + 0x7FFFu + ((u >> 16) & 1u);   // RNE
    return (unsigned short)(r >> 16);
}
__device__ inline float bf2f(unsigned short u) {
    union { unsigned u; float f; } v; v.u = ((unsigned)u) << 16; return v.f;
}

// async global->LDS, 16B per lane. LDS dest must be linear (wave base + lane*16);
// swizzle is pre-applied to the GLOBAL layout (m173 pattern: both-sides-or-neither).
__device__ __forceinline__ void gload16(const void* g, void* l) {
    __builtin_amdgcn_global_load_lds(
        (const __attribute__((address_space(1))) unsigned int*)g,
        (__attribute__((address_space(3))) unsigned int*)l,
        16, 0, 0);
}

// ---------------------------------------------------------------------------
// prep: blocks [0,42) zero counts+colsum+colsumsq; [42,554) Bt transpose
// (bf16, XOR-swizzled); [554,...) X fp32->bf16 (XOR-swizzled, zero-padded to
// Mpad rows so the GEMM staging needs no row guard).
// Swizzle: element index k ^= ((row & 7) << 3)  (i.e. byte ^= (row&7)<<4) —
// makes the linear-LDS ds_read_b128 pattern conflict-free (G4 / T2).
// ---------------------------------------------------------------------------
__global__ void prep_kernel(const float* __restrict__ X,
                            const float* __restrict__ Wl, const float* __restrict__ Wr,
                            int* __restrict__ zero_base, int nzero,
                            unsigned short* __restrict__ Bt,
                            unsigned short* __restrict__ Xbf, int N) {
    int b = blockIdx.x;
    if (b < 42) {
        int idx = b * 256 + threadIdx.x;
        if (idx < nzero) zero_base[idx] = 0;
    } else if (b < 42 + 512) {
        int n = b - 42;               // 0..511
        int k = threadIdx.x;          // 0..255
        const float* W = (n < 256) ? Wl : Wr;
        int nn = n & 255;
        int ks = k ^ ((n & 7) << 3);  // swizzled element slot
        Bt[(size_t)n * 256 + ks] = f2bf(W[(size_t)k * 256 + nn]);
    } else {
        int idx = (b - 554) * 256 + threadIdx.x;   // one 16B chunk (8 elems) each
        int row = idx >> 5;                        // 0..Mpad-1
        int k0 = (idx & 31) * 8;                   // element base, multiple of 8
        int ks = k0 ^ ((row & 7) << 3);            // swizzled chunk slot
        ushort8 v = {0, 0, 0, 0, 0, 0, 0, 0};
        if (row < N) {
            const float* src = X + (size_t)row * 256 + k0;
            float4 f0 = *(const float4*)(src);
            float4 f1 = *(const float4*)(src + 4);
            v[0] = f2bf(f0.x); v[1] = f2bf(f0.y);
            v[2] = f2bf(f0.z); v[3] = f2bf(f0.w);
            v[4] = f2bf(f1.x); v[5] = f2bf(f1.y);
            v[6] = f2bf(f1.z); v[7] = f2bf(f1.w);
        }
        *(ushort8*)(Xbf + (size_t)row * 256 + ks) = v;   // pad rows -> zeros
    }
}

// ---------------------------------------------------------------------------
// gemm_scatter: blocks [0,ngemm) = 64x64 MFMA GEMM tiles. Staging is now pure
// global_load_lds width-16 (no f2bf, no reg round-trip, no LDS writes): both
// Xbf and Bt are pre-converted bf16 with the st-16B XOR swizzle baked into
// their global layout, so linear LDS + swizzled ds_read is conflict-free.
// blocks [ngemm,...) = per-dst edge slot scatter (unchanged).
// ---------------------------------------------------------------------------
__global__ __launch_bounds__(256) void gemm_scatter_kernel(
    const unsigned short* __restrict__ Xbf, const unsigned short* __restrict__ Bt,
    const float* __restrict__ bl, const float* __restrict__ br,
    const int* __restrict__ ei, int* __restrict__ counts, int* __restrict__ ssrc,
    unsigned short* __restrict__ xlbf, float* __restrict__ xr,
    int M, int E, int N, int ngemm)
{
    if ((int)blockIdx.x >= ngemm) {
        int e = (blockIdx.x - ngemm) * 256 + threadIdx.x;
        if (e < E + N) {
            int src, dst;
            if (e < E) { src = ei[e]; dst = ei[E + e]; }
            else       { src = dst = e - E; }          // self-loop
            int pos = atomicAdd(&counts[dst], 1);
            if (pos < CAP) ssrc[dst * CAP + pos] = src;
        }
        return;
    }

    __shared__ __align__(16) unsigned short As[64 * 128];   // linear, swizzled content
    __shared__ __align__(16) unsigned short Bs[64 * 128];

    const int tid = threadIdx.x;
    const int wave = tid >> 6, lane = tid & 63;
    const int m_l = lane & 15, quad = lane >> 4;
    const int row0 = (blockIdx.x >> 3) * 64;
    const int n0 = (blockIdx.x & 7) * 64;
    const int sw = (m_l & 7) << 3;                  // read-side XOR (elements)

    f32x4 acc[4] = {};

    for (int k0 = 0; k0 < 256; k0 += 128) {
        __syncthreads();
        #pragma unroll
        for (int i = 0; i < 4; i++) {
            int L = (tid + i * 256) * 16;           // LDS byte offset 0..16368
            int r = L >> 8;                         // tile row 0..63
            int cb = L & 255;                       // byte within 128-elem half
            gload16((const char*)Xbf + (size_t)(row0 + r) * 512 + (size_t)k0 * 2 + cb,
                    (char*)As + L);
            gload16((const char*)Bt + (size_t)(n0 + r) * 512 + (size_t)k0 * 2 + cb,
                    (char*)Bs + L);
        }
        __syncthreads();   // compiler drains vmcnt here (m97 pattern)

        #pragma unroll
        for (int kk0 = 0; kk0 < 128; kk0 += 32) {
            int ka = (kk0 + quad * 8) ^ sw;         // swizzled element index
            bf16x8 a = *(const bf16x8*)&As[(wave * 16 + m_l) * 128 + ka];
            #pragma unroll
            for (int c = 0; c < 4; c++) {
                bf16x8 b = *(const bf16x8*)&Bs[(c * 16 + m_l) * 128 + ka];
                acc[c] = __builtin_amdgcn_mfma_f32_16x16x32_bf16(a, b, acc[c], 0, 0, 0);
            }
        }
    }

    const bool isl = (n0 < 256);
    #pragma unroll
    for (int c = 0; c < 4; c++) {
        int col = n0 + c * 16 + m_l;
        int cc = col & 255;
        float bv = isl ? bl[cc] : br[cc];
        #pragma unroll
        for (int r = 0; r < 4; r++) {
            int row = row0 + wave * 16 + quad * 4 + r;
            if (row < M) {
                float v = acc[c][r] + bv;
                if (isl) xlbf[(size_t)row * 256 + cc] = f2bf(v);
                else     xr[(size_t)row * 256 + cc] = v;
            }
        }
    }
}

// ---------------------------------------------------------------------------
// node: 2500 blocks x 4 waves, ONE NODE PER WAVE (no LDS, no barriers).
// Lane owns 8 dims (16B ushort8 gathers); two half-wave edge streams,
// 4-deep prefetch, combine via shfl_xor(32). Fused bias+ReLU+dropout.
// (R11 winner — do NOT fold BN here: 2500 same-address global atomics
//  per column serialize to ~50 µs, measured R12.)
// ---------------------------------------------------------------------------
__device__ inline float dot8leaky(const float* f, float4 bA, float4 bB,
                                  float4 aA, float4 aB) {
    float h, s = 0.f;
    h = f[0] + bA.x; h = (h > 0.f) ? h : NEG_SLOPE * h; s += h * aA.x;
    h = f[1] + bA.y; h = (h > 0.f) ? h : NEG_SLOPE * h; s += h * aA.y;
    h = f[2] + bA.z; h = (h > 0.f) ? h : NEG_SLOPE * h; s += h * aA.z;
    h = f[3] + bA.w; h = (h > 0.f) ? h : NEG_SLOPE * h; s += h * aA.w;
    h = f[4] + bB.x; h = (h > 0.f) ? h : NEG_SLOPE * h; s += h * aB.x;
    h = f[5] + bB.y; h = (h > 0.f) ? h : NEG_SLOPE * h; s += h * aB.y;
    h = f[6] + bB.z; h = (h > 0.f) ? h : NEG_SLOPE * h; s += h * aB.z;
    h = f[7] + bB.w; h = (h > 0.f) ? h : NEG_SLOPE * h; s += h * aB.w;
    return s;
}

__global__ __launch_bounds__(256) void node_kernel(
    const unsigned short* __restrict__ xlbf, const float* __restrict__ xr,
    const float* __restrict__ att, const float* __restrict__ bias,
    const float* __restrict__ du, const int* __restrict__ counts,
    const int* __restrict__ ssrc, float* __restrict__ out, int N)
{
    const int wave = threadIdx.x >> 6, lane = threadIdx.x & 63;
    const int i = blockIdx.x * 4 + wave;
    if (i >= N) return;
    const int hl = lane & 31;
    const int sid = lane >> 5;                  // stream 0 or 1

    const float4 attA = ((const float4*)att)[hl * 2];
    const float4 attB = ((const float4*)att)[hl * 2 + 1];
    const float4 bA = ((const float4*)(xr + (size_t)i * D))[hl * 2];
    const float4 bB = ((const float4*)(xr + (size_t)i * D))[hl * 2 + 1];

    int cnt = counts[i];
    if (cnt > CAP) cnt = CAP;
    const int start = i * CAP, end = start + cnt;

    float m = -INFINITY, lsum = 0.f;
    float acc[8] = {0.f, 0.f, 0.f, 0.f, 0.f, 0.f, 0.f, 0.f};
    const ushort8 z8 = {0, 0, 0, 0, 0, 0, 0, 0};

    int e = start + sid;                        // stream edges: e, e+2, e+4, ...
    ushort8 p0, p1, p2, p3;
    p0 = (e     < end) ? *(const ushort8*)(xlbf + (size_t)ssrc[e]     * D + hl * 8) : z8;
    p1 = (e + 2 < end) ? *(const ushort8*)(xlbf + (size_t)ssrc[e + 2] * D + hl * 8) : z8;
    p2 = (e + 4 < end) ? *(const ushort8*)(xlbf + (size_t)ssrc[e + 4] * D + hl * 8) : z8;
    p3 = (e + 6 < end) ? *(const ushort8*)(xlbf + (size_t)ssrc[e + 6] * D + hl * 8) : z8;

    while (e < end) {
        ushort8 c0 = p0, c1 = p1, c2 = p2, c3 = p3;
        bool v1 = (e + 2 < end), v2 = (e + 4 < end), v3 = (e + 6 < end);
        int en = e + 8;
        p0 = (en     < end) ? *(const ushort8*)(xlbf + (size_t)ssrc[en]     * D + hl * 8) : z8;
        p1 = (en + 2 < end) ? *(const ushort8*)(xlbf + (size_t)ssrc[en + 2] * D + hl * 8) : z8;
        p2 = (en + 4 < end) ? *(const ushort8*)(xlbf + (size_t)ssrc[en + 4] * D + hl * 8) : z8;
        p3 = (en + 6 < end) ? *(const ushort8*)(xlbf + (size_t)ssrc[en + 6] * D + hl * 8) : z8;

        float f0[8], f1[8], f2[8], f3[8];
        #pragma unroll
        for (int k = 0; k < 8; k++) {
            f0[k] = bf2f(c0[k]); f1[k] = bf2f(c1[k]);
            f2[k] = bf2f(c2[k]); f3[k] = bf2f(c3[k]);
        }

        float s0 = dot8leaky(f0, bA, bB, attA, attB);
        float s1 = dot8leaky(f1, bA, bB, attA, attB);
        float s2 = dot8leaky(f2, bA, bB, attA, attB);
        float s3 = dot8leaky(f3, bA, bB, attA, attB);

        #pragma unroll
        for (int off = 1; off < 32; off <<= 1) {    // 5-step, within half-wave
            s0 += __shfl_xor(s0, off);
            s1 += __shfl_xor(s1, off);
            s2 += __shfl_xor(s2, off);
            s3 += __shfl_xor(s3, off);
        }
        if (!v1) s1 = -INFINITY;
        if (!v2) s2 = -INFINITY;
        if (!v3) s3 = -INFINITY;

        float mnew = fmaxf(fmaxf(m, fmaxf(s0, s1)), fmaxf(s2, s3));
        float sc = __expf(m - mnew);                 // exp(-inf-finite)=0, safe
        float e0e = __expf(s0 - mnew);
        float e1e = __expf(s1 - mnew);
        float e2e = __expf(s2 - mnew);
        float e3e = __expf(s3 - mnew);
        lsum = lsum * sc + e0e + e1e + e2e + e3e;
        #pragma unroll
        for (int k = 0; k < 8; k++) {
            acc[k] = acc[k] * sc + e0e * f0[k] + e1e * f1[k]
                                 + e2e * f2[k] + e3e * f3[k];
        }
        m = mnew;
        e = en;
    }

    // combine the two half-wave streams (guard -inf - -inf = nan; stream 1 may
    // be empty for degree-1 nodes, stream 0 always has the self-loop)
    {
        float mO = __shfl_xor(m, 32);
        float lO = __shfl_xor(lsum, 32);
        float accO[8];
        #pragma unroll
        for (int k = 0; k < 8; k++) accO[k] = __shfl_xor(acc[k], 32);
        float mn = fmaxf(m, mO);
        float wS = (m  == -INFINITY) ? 0.f : __expf(m - mn);
        float wO = (mO == -INFINITY) ? 0.f : __expf(mO - mn);
        lsum = lsum * wS + lO * wO;
        #pragma unroll
        for (int k = 0; k < 8; k++) acc[k] = acc[k] * wS + accO[k] * wO;
    }

    if (lane < 32) {
        float inv = 1.f / lsum;
        float4 biA = ((const float4*)bias)[hl * 2];
        float4 biB = ((const float4*)bias)[hl * 2 + 1];
        float4 uA = ((const float4*)(du + (size_t)i * D))[hl * 2];
        float4 uB = ((const float4*)(du + (size_t)i * D))[hl * 2 + 1];
        float4 oA, oB;
        oA.x = fmaxf(acc[0] * inv + biA.x, 0.f); oA.x = (uA.x >= 0.5f) ? 2.f * oA.x : 0.f;
        oA.y = fmaxf(acc[1] * inv + biA.y, 0.f); oA.y = (uA.y >= 0.5f) ? 2.f * oA.y : 0.f;
        oA.z = fmaxf(acc[2] * inv + biA.z, 0.f); oA.z = (uA.z >= 0.5f) ? 2.f * oA.z : 0.f;
        oA.w = fmaxf(acc[3] * inv + biA.w, 0.f); oA.w = (uA.w >= 0.5f) ? 2.f * oA.w : 0.f;
        oB.x = fmaxf(acc[4] * inv + biB.x, 0.f); oB.x = (uB.x >= 0.5f) ? 2.f * oB.x : 0.f;
        oB.y = fmaxf(acc[5] * inv + biB.y, 0.f); oB.y = (uB.y >= 0.5f) ? 2.f * oB.y : 0.f;
        oB.z = fmaxf(acc[6] * inv + biB.z, 0.f); oB.z = (uB.z >= 0.5f) ? 2.f * oB.z : 0.f;
        oB.w = fmaxf(acc[7] * inv + biB.w, 0.f); oB.w = (uB.w >= 0.5f) ? 2.f * oB.w : 0.f;
        ((float4*)(out + (size_t)i * D))[hl * 2] = oA;
        ((float4*)(out + (size_t)i * D))[hl * 2 + 1] = oB;
    }
}

// ---------------------------------------------------------------------------
// BatchNorm (training stats): 256 blocks -> only 256 atomics per address
// ---------------------------------------------------------------------------
__global__ void bn_reduce_kernel(const float* __restrict__ pre,
                                 float* __restrict__ colsum,
                                 float* __restrict__ colsumsq, int N) {
    int t = threadIdx.x;
    float s = 0.f, s2 = 0.f;
    for (int r = blockIdx.x; r < N; r += gridDim.x) {
        float v = pre[(size_t)r * D + t];
        s += v; s2 += v * v;
    }
    atomicAdd(&colsum[t], s);
    atomicAdd(&colsumsq[t], s2);
}

__global__ void bn_apply_kernel(float* __restrict__ out,
                                const float* __restrict__ colsum,
                                const float* __restrict__ colsumsq,
                                const float* __restrict__ gamma,
                                const float* __restrict__ beta, int N) {
    int idx4 = blockIdx.x * 256 + threadIdx.x;
    int t0 = (idx4 * 4) & (D - 1);
    float invN = 1.f / (float)N;
    float4 v = ((const float4*)out)[idx4];
    float4 o;
    #pragma unroll
    for (int j = 0; j < 4; j++) {
        float mean = colsum[t0 + j] * invN;
        float var = colsumsq[t0 + j] * invN - mean * mean;
        float r = rsqrtf(var + BN_EPS);
        float vv = (j == 0) ? v.x : (j == 1) ? v.y : (j == 2) ? v.z : v.w;
        float oo = gamma[t0 + j] * (vv - mean) * r + beta[t0 + j];
        if (j == 0) o.x = oo; else if (j == 1) o.y = oo; else if (j == 2) o.z = oo; else o.w = oo;
    }
    ((float4*)out)[idx4] = o;
}

// ---------------------------------------------------------------------------
extern "C" void kernel_launch(void* const* d_in, const int* in_sizes, int n_in,
                              void* d_out, int out_size, void* d_ws, size_t ws_size,
                              hipStream_t stream) {
    const float* x     = (const float*)d_in[0];
    const int*   ei    = (const int*)d_in[1];
    const float* Wl    = (const float*)d_in[2];
    const float* bl    = (const float*)d_in[3];
    const float* Wr    = (const float*)d_in[4];
    const float* br    = (const float*)d_in[5];
    const float* att   = (const float*)d_in[6];
    const float* bias  = (const float*)d_in[7];
    const float* gamma = (const float*)d_in[8];
    const float* beta  = (const float*)d_in[9];
    const float* du    = (const float*)d_in[10];

    const int N = in_sizes[0] / D;       // 10000
    const int E = in_sizes[1] / 2;       // 160000
    const int Mpad = (N + 63) & ~63;     // 10048: zero-padded rows for guard-free staging

    // workspace layout (4-byte word units)
    int* ws = (int*)d_ws;
    size_t off = 0;
    float* xr       = (float*)(ws + off); off += (size_t)N * D;
    unsigned short* xlbf = (unsigned short*)(ws + off); off += (size_t)N * D / 2;
    unsigned short* Xbf  = (unsigned short*)(ws + off); off += (size_t)Mpad * D / 2;
    unsigned short* Bt   = (unsigned short*)(ws + off); off += 512 * 256 / 2;
    int*   ssrc     = ws + off;           off += (size_t)N * CAP;
    // contiguous zeroed region (zeroed by prep_kernel blocks 0..41):
    float* colsum   = (float*)(ws + off); off += D;
    float* colsumsq = (float*)(ws + off); off += D;
    int*   counts   = ws + off;           off += N;
    int nzero = 2 * D + N;               // 10512 words

    int nconv = (Mpad * 32) / 256;       // 1256 blocks, 8 elems/thread
    prep_kernel<<<42 + 512 + nconv, 256, 0, stream>>>(
        x, Wl, Wr, (int*)colsum, nzero, Bt, Xbf, N);

    int nMtiles = (N + 63) / 64;         // 157
    int ngemm = nMtiles * 8;             // 1256
    int nscat = (E + N + 255) / 256;     // 665
    gemm_scatter_kernel<<<ngemm + nscat, 256, 0, stream>>>(
        Xbf, Bt, bl, br, ei, counts, ssrc, xlbf, xr, N, E, N, ngemm);

    node_kernel<<<(N + 3) / 4, 256, 0, stream>>>(
        xlbf, xr, att, bias, du, counts, ssrc, (float*)d_out, N);

    bn_reduce_kernel<<<256, 256, 0, stream>>>((const float*)d_out, colsum, colsumsq, N);
    bn_apply_kernel<<<(N * D / 4 + 255) / 256, 256, 0, stream>>>(
        (float*)d_out, colsum, colsumsq, gamma, beta, N);
}

// Round 2
// 148.711 us; speedup vs baseline: 1.1271x; 1.0822x over previous
//
#include <hip/hip_runtime.h>
#include <hip/hip_bf16.h>
#include <math.h>

// N=10000, E=160000, DIN=DOUT=256. edge_index is int32 (verified R4/R5).
#define D 256
#define CAP 128           // per-node edge slots; max degree ~45 for this graph
#define NEG_SLOPE 0.2f
#define BN_EPS 1e-5f

typedef __attribute__((ext_vector_type(8))) short bf16x8;
typedef __attribute__((ext_vector_type(8))) unsigned short ushort8;
typedef __attribute__((ext_vector_type(4))) float f32x4;

__device__ inline unsigned short f2bf(float f) {
    union { float f; unsigned u; } v; v.f = f;
    unsigned u = v.u;
    unsigned r = u + 0x7FFFu + ((u >> 16) & 1u);   // RNE
    return (unsigned short)(r >> 16);
}
__device__ inline float bf2f(unsigned short u) {
    union { unsigned u; float f; } v; v.u = ((unsigned)u) << 16; return v.f;
}

// async global->LDS, 16B per lane. LDS dest must be linear (wave base + lane*16);
// swizzle is pre-applied to the GLOBAL layout (m173 pattern: both-sides-or-neither).
__device__ __forceinline__ void gload16(const void* g, void* l) {
    __builtin_amdgcn_global_load_lds(
        (const __attribute__((address_space(1))) unsigned int*)g,
        (__attribute__((address_space(3))) unsigned int*)l,
        16, 0, 0);
}

// ---------------------------------------------------------------------------
// prep: blocks [0,42) zero counts+colsum+colsumsq; [42,554) Bt transpose
// (bf16, XOR-swizzled); [554,...) X fp32->bf16 (XOR-swizzled, zero-padded to
// Mpad rows so the GEMM staging needs no row guard).
// Swizzle: element index k ^= ((row & 7) << 3)  (i.e. byte ^= (row&7)<<4) —
// makes the linear-LDS ds_read_b128 pattern conflict-free (G4 / T2).
// ---------------------------------------------------------------------------
__global__ void prep_kernel(const float* __restrict__ X,
                            const float* __restrict__ Wl, const float* __restrict__ Wr,
                            int* __restrict__ zero_base, int nzero,
                            unsigned short* __restrict__ Bt,
                            unsigned short* __restrict__ Xbf, int N) {
    int b = blockIdx.x;
    if (b < 42) {
        int idx = b * 256 + threadIdx.x;
        if (idx < nzero) zero_base[idx] = 0;
    } else if (b < 42 + 512) {
        int n = b - 42;               // 0..511
        int k = threadIdx.x;          // 0..255
        const float* W = (n < 256) ? Wl : Wr;
        int nn = n & 255;
        int ks = k ^ ((n & 7) << 3);  // swizzled element slot
        Bt[(size_t)n * 256 + ks] = f2bf(W[(size_t)k * 256 + nn]);
    } else {
        int idx = (b - 554) * 256 + threadIdx.x;   // one 16B chunk (8 elems) each
        int row = idx >> 5;                        // 0..Mpad-1
        int k0 = (idx & 31) * 8;                   // element base, multiple of 8
        int ks = k0 ^ ((row & 7) << 3);            // swizzled chunk slot
        ushort8 v = {0, 0, 0, 0, 0, 0, 0, 0};
        if (row < N) {
            const float* src = X + (size_t)row * 256 + k0;
            float4 f0 = *(const float4*)(src);
            float4 f1 = *(const float4*)(src + 4);
            v[0] = f2bf(f0.x); v[1] = f2bf(f0.y);
            v[2] = f2bf(f0.z); v[3] = f2bf(f0.w);
            v[4] = f2bf(f1.x); v[5] = f2bf(f1.y);
            v[6] = f2bf(f1.z); v[7] = f2bf(f1.w);
        }
        *(ushort8*)(Xbf + (size_t)row * 256 + ks) = v;   // pad rows -> zeros
    }
}

// ---------------------------------------------------------------------------
// gemm_scatter: blocks [0,ngemm) = 64x64 MFMA GEMM tiles. Staging is pure
// global_load_lds width-16 (no f2bf, no reg round-trip, no LDS writes): both
// Xbf and Bt are pre-converted bf16 with the st-16B XOR swizzle baked into
// their global layout, so linear LDS + swizzled ds_read is conflict-free.
// blocks [ngemm,...) = per-dst edge slot scatter.
// ---------------------------------------------------------------------------
__global__ __launch_bounds__(256) void gemm_scatter_kernel(
    const unsigned short* __restrict__ Xbf, const unsigned short* __restrict__ Bt,
    const float* __restrict__ bl, const float* __restrict__ br,
    const int* __restrict__ ei, int* __restrict__ counts, int* __restrict__ ssrc,
    unsigned short* __restrict__ xlbf, float* __restrict__ xr,
    int M, int E, int N, int ngemm)
{
    if ((int)blockIdx.x >= ngemm) {
        int e = (blockIdx.x - ngemm) * 256 + threadIdx.x;
        if (e < E + N) {
            int src, dst;
            if (e < E) { src = ei[e]; dst = ei[E + e]; }
            else       { src = dst = e - E; }          // self-loop
            int pos = atomicAdd(&counts[dst], 1);
            if (pos < CAP) ssrc[dst * CAP + pos] = src;
        }
        return;
    }

    __shared__ __align__(16) unsigned short As[64 * 128];   // linear, swizzled content
    __shared__ __align__(16) unsigned short Bs[64 * 128];

    const int tid = threadIdx.x;
    const int wave = tid >> 6, lane = tid & 63;
    const int m_l = lane & 15, quad = lane >> 4;
    const int row0 = (blockIdx.x >> 3) * 64;
    const int n0 = (blockIdx.x & 7) * 64;
    const int sw = (m_l & 7) << 3;                  // read-side XOR (elements)

    f32x4 acc[4] = {};

    for (int k0 = 0; k0 < 256; k0 += 128) {
        __syncthreads();
        #pragma unroll
        for (int i = 0; i < 4; i++) {
            int L = (tid + i * 256) * 16;           // LDS byte offset 0..16368
            int r = L >> 8;                         // tile row 0..63
            int cb = L & 255;                       // byte within 128-elem half
            gload16((const char*)Xbf + (size_t)(row0 + r) * 512 + (size_t)k0 * 2 + cb,
                    (char*)As + L);
            gload16((const char*)Bt + (size_t)(n0 + r) * 512 + (size_t)k0 * 2 + cb,
                    (char*)Bs + L);
        }
        __syncthreads();   // compiler drains vmcnt here (m97 pattern)

        #pragma unroll
        for (int kk0 = 0; kk0 < 128; kk0 += 32) {
            int ka = (kk0 + quad * 8) ^ sw;         // swizzled element index
            bf16x8 a = *(const bf16x8*)&As[(wave * 16 + m_l) * 128 + ka];
            #pragma unroll
            for (int c = 0; c < 4; c++) {
                bf16x8 b = *(const bf16x8*)&Bs[(c * 16 + m_l) * 128 + ka];
                acc[c] = __builtin_amdgcn_mfma_f32_16x16x32_bf16(a, b, acc[c], 0, 0, 0);
            }
        }
    }

    const bool isl = (n0 < 256);
    #pragma unroll
    for (int c = 0; c < 4; c++) {
        int col = n0 + c * 16 + m_l;
        int cc = col & 255;
        float bv = isl ? bl[cc] : br[cc];
        #pragma unroll
        for (int r = 0; r < 4; r++) {
            int row = row0 + wave * 16 + quad * 4 + r;
            if (row < M) {
                float v = acc[c][r] + bv;
                if (isl) xlbf[(size_t)row * 256 + cc] = f2bf(v);
                else     xr[(size_t)row * 256 + cc] = v;
            }
        }
    }
}

// ---------------------------------------------------------------------------
// node: 2500 blocks x 4 waves, ONE NODE PER WAVE (no LDS, no barriers).
// Lane owns 8 dims (16B ushort8 gathers); two half-wave edge streams,
// 4-deep prefetch, combine via shfl_xor(32). Fused bias+ReLU+dropout.
// NEW (this round): the node's adjacency list is preloaded into a register
// with ONE coalesced load (deg<=45 < 64); per-edge gather addresses come
// from __shfl instead of dependent ssrc[] global loads — removes the
// L2-latency link at the head of every prefetch chain. Cold fallback path
// (original per-iteration loads) kept for cnt>64.
// (R11 winner — do NOT fold BN here: 2500 same-address global atomics
//  per column serialize to ~50 µs, measured R12.)
// ---------------------------------------------------------------------------
__device__ inline float dot8leaky(const float* f, float4 bA, float4 bB,
                                  float4 aA, float4 aB) {
    float h, s = 0.f;
    h = f[0] + bA.x; h = (h > 0.f) ? h : NEG_SLOPE * h; s += h * aA.x;
    h = f[1] + bA.y; h = (h > 0.f) ? h : NEG_SLOPE * h; s += h * aA.y;
    h = f[2] + bA.z; h = (h > 0.f) ? h : NEG_SLOPE * h; s += h * aA.z;
    h = f[3] + bA.w; h = (h > 0.f) ? h : NEG_SLOPE * h; s += h * aA.w;
    h = f[4] + bB.x; h = (h > 0.f) ? h : NEG_SLOPE * h; s += h * aB.x;
    h = f[5] + bB.y; h = (h > 0.f) ? h : NEG_SLOPE * h; s += h * aB.y;
    h = f[6] + bB.z; h = (h > 0.f) ? h : NEG_SLOPE * h; s += h * aB.z;
    h = f[7] + bB.w; h = (h > 0.f) ? h : NEG_SLOPE * h; s += h * aB.w;
    return s;
}

__global__ __launch_bounds__(256) void node_kernel(
    const unsigned short* __restrict__ xlbf, const float* __restrict__ xr,
    const float* __restrict__ att, const float* __restrict__ bias,
    const float* __restrict__ du, const int* __restrict__ counts,
    const int* __restrict__ ssrc, float* __restrict__ out, int N)
{
    const int wave = threadIdx.x >> 6, lane = threadIdx.x & 63;
    const int i = blockIdx.x * 4 + wave;
    if (i >= N) return;
    const int hl = lane & 31;
    const int sid = lane >> 5;                  // stream 0 or 1

    int cnt = counts[i];
    if (cnt > CAP) cnt = CAP;
    const int start = i * CAP, end = start + cnt;

    // one coalesced load grabs the whole adjacency list (issued early so its
    // latency overlaps the xr/att loads below)
    int srcv = (lane < cnt) ? ssrc[start + lane] : 0;

    const float4 attA = ((const float4*)att)[hl * 2];
    const float4 attB = ((const float4*)att)[hl * 2 + 1];
    const float4 bA = ((const float4*)(xr + (size_t)i * D))[hl * 2];
    const float4 bB = ((const float4*)(xr + (size_t)i * D))[hl * 2 + 1];

    float m = -INFINITY, lsum = 0.f;
    float acc[8] = {0.f, 0.f, 0.f, 0.f, 0.f, 0.f, 0.f, 0.f};
    const ushort8 z8 = {0, 0, 0, 0, 0, 0, 0, 0};
    const unsigned short* xb = xlbf + hl * 8;

    int e = start + sid;                        // stream edges: e, e+2, e+4, ...

    if (cnt <= 64) {
        // ---- fast path: register adjacency, shfl addressing ----
        ushort8 p0, p1, p2, p3;
        {
            int o = sid;                        // ordinal of first edge in stream
            int a0 = __shfl(srcv, o);
            int a1 = __shfl(srcv, o + 2);
            int a2 = __shfl(srcv, o + 4);
            int a3 = __shfl(srcv, o + 6);
            p0 = (e     < end) ? *(const ushort8*)(xb + (size_t)a0 * D) : z8;
            p1 = (e + 2 < end) ? *(const ushort8*)(xb + (size_t)a1 * D) : z8;
            p2 = (e + 4 < end) ? *(const ushort8*)(xb + (size_t)a2 * D) : z8;
            p3 = (e + 6 < end) ? *(const ushort8*)(xb + (size_t)a3 * D) : z8;
        }

        while (e < end) {
            ushort8 c0 = p0, c1 = p1, c2 = p2, c3 = p3;
            bool v1 = (e + 2 < end), v2 = (e + 4 < end), v3 = (e + 6 < end);
            int en = e + 8;
            {
                int on = en - start;            // next ordinal base (per-lane via sid)
                int a0 = __shfl(srcv, on);
                int a1 = __shfl(srcv, on + 2);
                int a2 = __shfl(srcv, on + 4);
                int a3 = __shfl(srcv, on + 6);
                p0 = (en     < end) ? *(const ushort8*)(xb + (size_t)a0 * D) : z8;
                p1 = (en + 2 < end) ? *(const ushort8*)(xb + (size_t)a1 * D) : z8;
                p2 = (en + 4 < end) ? *(const ushort8*)(xb + (size_t)a2 * D) : z8;
                p3 = (en + 6 < end) ? *(const ushort8*)(xb + (size_t)a3 * D) : z8;
            }

            float f0[8], f1[8], f2[8], f3[8];
            #pragma unroll
            for (int k = 0; k < 8; k++) {
                f0[k] = bf2f(c0[k]); f1[k] = bf2f(c1[k]);
                f2[k] = bf2f(c2[k]); f3[k] = bf2f(c3[k]);
            }

            float s0 = dot8leaky(f0, bA, bB, attA, attB);
            float s1 = dot8leaky(f1, bA, bB, attA, attB);
            float s2 = dot8leaky(f2, bA, bB, attA, attB);
            float s3 = dot8leaky(f3, bA, bB, attA, attB);

            #pragma unroll
            for (int off = 1; off < 32; off <<= 1) {    // 5-step, within half-wave
                s0 += __shfl_xor(s0, off);
                s1 += __shfl_xor(s1, off);
                s2 += __shfl_xor(s2, off);
                s3 += __shfl_xor(s3, off);
            }
            if (!v1) s1 = -INFINITY;
            if (!v2) s2 = -INFINITY;
            if (!v3) s3 = -INFINITY;

            float mnew = fmaxf(fmaxf(m, fmaxf(s0, s1)), fmaxf(s2, s3));
            float sc = __expf(m - mnew);                 // exp(-inf-finite)=0, safe
            float e0e = __expf(s0 - mnew);
            float e1e = __expf(s1 - mnew);
            float e2e = __expf(s2 - mnew);
            float e3e = __expf(s3 - mnew);
            lsum = lsum * sc + e0e + e1e + e2e + e3e;
            #pragma unroll
            for (int k = 0; k < 8; k++) {
                acc[k] = acc[k] * sc + e0e * f0[k] + e1e * f1[k]
                                     + e2e * f2[k] + e3e * f3[k];
            }
            m = mnew;
            e = en;
        }
    } else {
        // ---- cold fallback (cnt > 64, impossible for this graph): original loop ----
        ushort8 p0, p1, p2, p3;
        p0 = (e     < end) ? *(const ushort8*)(xb + (size_t)ssrc[e]     * D) : z8;
        p1 = (e + 2 < end) ? *(const ushort8*)(xb + (size_t)ssrc[e + 2] * D) : z8;
        p2 = (e + 4 < end) ? *(const ushort8*)(xb + (size_t)ssrc[e + 4] * D) : z8;
        p3 = (e + 6 < end) ? *(const ushort8*)(xb + (size_t)ssrc[e + 6] * D) : z8;

        while (e < end) {
            ushort8 c0 = p0, c1 = p1, c2 = p2, c3 = p3;
            bool v1 = (e + 2 < end), v2 = (e + 4 < end), v3 = (e + 6 < end);
            int en = e + 8;
            p0 = (en     < end) ? *(const ushort8*)(xb + (size_t)ssrc[en]     * D) : z8;
            p1 = (en + 2 < end) ? *(const ushort8*)(xb + (size_t)ssrc[en + 2] * D) : z8;
            p2 = (en + 4 < end) ? *(const ushort8*)(xb + (size_t)ssrc[en + 4] * D) : z8;
            p3 = (en + 6 < end) ? *(const ushort8*)(xb + (size_t)ssrc[en + 6] * D) : z8;

            float f0[8], f1[8], f2[8], f3[8];
            #pragma unroll
            for (int k = 0; k < 8; k++) {
                f0[k] = bf2f(c0[k]); f1[k] = bf2f(c1[k]);
                f2[k] = bf2f(c2[k]); f3[k] = bf2f(c3[k]);
            }

            float s0 = dot8leaky(f0, bA, bB, attA, attB);
            float s1 = dot8leaky(f1, bA, bB, attA, attB);
            float s2 = dot8leaky(f2, bA, bB, attA, attB);
            float s3 = dot8leaky(f3, bA, bB, attA, attB);

            #pragma unroll
            for (int off = 1; off < 32; off <<= 1) {
                s0 += __shfl_xor(s0, off);
                s1 += __shfl_xor(s1, off);
                s2 += __shfl_xor(s2, off);
                s3 += __shfl_xor(s3, off);
            }
            if (!v1) s1 = -INFINITY;
            if (!v2) s2 = -INFINITY;
            if (!v3) s3 = -INFINITY;

            float mnew = fmaxf(fmaxf(m, fmaxf(s0, s1)), fmaxf(s2, s3));
            float sc = __expf(m - mnew);
            float e0e = __expf(s0 - mnew);
            float e1e = __expf(s1 - mnew);
            float e2e = __expf(s2 - mnew);
            float e3e = __expf(s3 - mnew);
            lsum = lsum * sc + e0e + e1e + e2e + e3e;
            #pragma unroll
            for (int k = 0; k < 8; k++) {
                acc[k] = acc[k] * sc + e0e * f0[k] + e1e * f1[k]
                                     + e2e * f2[k] + e3e * f3[k];
            }
            m = mnew;
            e = en;
        }
    }

    // combine the two half-wave streams (guard -inf - -inf = nan; stream 1 may
    // be empty for degree-1 nodes, stream 0 always has the self-loop)
    {
        float mO = __shfl_xor(m, 32);
        float lO = __shfl_xor(lsum, 32);
        float accO[8];
        #pragma unroll
        for (int k = 0; k < 8; k++) accO[k] = __shfl_xor(acc[k], 32);
        float mn = fmaxf(m, mO);
        float wS = (m  == -INFINITY) ? 0.f : __expf(m - mn);
        float wO = (mO == -INFINITY) ? 0.f : __expf(mO - mn);
        lsum = lsum * wS + lO * wO;
        #pragma unroll
        for (int k = 0; k < 8; k++) acc[k] = acc[k] * wS + accO[k] * wO;
    }

    if (lane < 32) {
        float inv = 1.f / lsum;
        float4 biA = ((const float4*)bias)[hl * 2];
        float4 biB = ((const float4*)bias)[hl * 2 + 1];
        float4 uA = ((const float4*)(du + (size_t)i * D))[hl * 2];
        float4 uB = ((const float4*)(du + (size_t)i * D))[hl * 2 + 1];
        float4 oA, oB;
        oA.x = fmaxf(acc[0] * inv + biA.x, 0.f); oA.x = (uA.x >= 0.5f) ? 2.f * oA.x : 0.f;
        oA.y = fmaxf(acc[1] * inv + biA.y, 0.f); oA.y = (uA.y >= 0.5f) ? 2.f * oA.y : 0.f;
        oA.z = fmaxf(acc[2] * inv + biA.z, 0.f); oA.z = (uA.z >= 0.5f) ? 2.f * oA.z : 0.f;
        oA.w = fmaxf(acc[3] * inv + biA.w, 0.f); oA.w = (uA.w >= 0.5f) ? 2.f * oA.w : 0.f;
        oB.x = fmaxf(acc[4] * inv + biB.x, 0.f); oB.x = (uB.x >= 0.5f) ? 2.f * oB.x : 0.f;
        oB.y = fmaxf(acc[5] * inv + biB.y, 0.f); oB.y = (uB.y >= 0.5f) ? 2.f * oB.y : 0.f;
        oB.z = fmaxf(acc[6] * inv + biB.z, 0.f); oB.z = (uB.z >= 0.5f) ? 2.f * oB.z : 0.f;
        oB.w = fmaxf(acc[7] * inv + biB.w, 0.f); oB.w = (uB.w >= 0.5f) ? 2.f * oB.w : 0.f;
        ((float4*)(out + (size_t)i * D))[hl * 2] = oA;
        ((float4*)(out + (size_t)i * D))[hl * 2 + 1] = oB;
    }
}

// ---------------------------------------------------------------------------
// BatchNorm (training stats). 128 blocks x 512 threads: 2 row-teams per block
// with 4-deep unrolled independent loads (MLP for latency hiding), LDS team
// combine, then ONE atomic per column per block -> 128 same-address atomics
// (~2.6 µs tail vs ~5 µs at 256).
// ---------------------------------------------------------------------------
__global__ __launch_bounds__(512) void bn_reduce_kernel(const float* __restrict__ pre,
                                 float* __restrict__ colsum,
                                 float* __restrict__ colsumsq, int N) {
    __shared__ float ls[256], ls2[256];
    const int col = threadIdx.x & 255;
    const int team = threadIdx.x >> 8;               // 0 or 1
    const int S = gridDim.x * 2;                     // 256 row-streams
    const int stream = blockIdx.x * 2 + team;
    float s = 0.f, s2 = 0.f;
    int r = stream;
    for (; r + 3 * S < N; r += 4 * S) {
        float v0 = pre[(size_t)r * D + col];
        float v1 = pre[(size_t)(r + S) * D + col];
        float v2 = pre[(size_t)(r + 2 * S) * D + col];
        float v3 = pre[(size_t)(r + 3 * S) * D + col];
        s += v0 + v1 + v2 + v3;
        s2 += v0 * v0 + v1 * v1 + v2 * v2 + v3 * v3;
    }
    for (; r < N; r += S) {
        float v = pre[(size_t)r * D + col];
        s += v; s2 += v * v;
    }
    if (team == 1) { ls[col] = s; ls2[col] = s2; }
    __syncthreads();
    if (team == 0) {
        s += ls[col]; s2 += ls2[col];
        atomicAdd(&colsum[col], s);
        atomicAdd(&colsumsq[col], s2);
    }
}

__global__ void bn_apply_kernel(float* __restrict__ out,
                                const float* __restrict__ colsum,
                                const float* __restrict__ colsumsq,
                                const float* __restrict__ gamma,
                                const float* __restrict__ beta, int N) {
    int idx4 = blockIdx.x * 256 + threadIdx.x;
    int t0 = (idx4 * 4) & (D - 1);
    float invN = 1.f / (float)N;
    float4 v = ((const float4*)out)[idx4];
    float4 o;
    #pragma unroll
    for (int j = 0; j < 4; j++) {
        float mean = colsum[t0 + j] * invN;
        float var = colsumsq[t0 + j] * invN - mean * mean;
        float r = rsqrtf(var + BN_EPS);
        float vv = (j == 0) ? v.x : (j == 1) ? v.y : (j == 2) ? v.z : v.w;
        float oo = gamma[t0 + j] * (vv - mean) * r + beta[t0 + j];
        if (j == 0) o.x = oo; else if (j == 1) o.y = oo; else if (j == 2) o.z = oo; else o.w = oo;
    }
    ((float4*)out)[idx4] = o;
}

// ---------------------------------------------------------------------------
extern "C" void kernel_launch(void* const* d_in, const int* in_sizes, int n_in,
                              void* d_out, int out_size, void* d_ws, size_t ws_size,
                              hipStream_t stream) {
    const float* x     = (const float*)d_in[0];
    const int*   ei    = (const int*)d_in[1];
    const float* Wl    = (const float*)d_in[2];
    const float* bl    = (const float*)d_in[3];
    const float* Wr    = (const float*)d_in[4];
    const float* br    = (const float*)d_in[5];
    const float* att   = (const float*)d_in[6];
    const float* bias  = (const float*)d_in[7];
    const float* gamma = (const float*)d_in[8];
    const float* beta  = (const float*)d_in[9];
    const float* du    = (const float*)d_in[10];

    const int N = in_sizes[0] / D;       // 10000
    const int E = in_sizes[1] / 2;       // 160000
    const int Mpad = (N + 63) & ~63;     // 10048: zero-padded rows for guard-free staging

    // workspace layout (4-byte word units)
    int* ws = (int*)d_ws;
    size_t off = 0;
    float* xr       = (float*)(ws + off); off += (size_t)N * D;
    unsigned short* xlbf = (unsigned short*)(ws + off); off += (size_t)N * D / 2;
    unsigned short* Xbf  = (unsigned short*)(ws + off); off += (size_t)Mpad * D / 2;
    unsigned short* Bt   = (unsigned short*)(ws + off); off += 512 * 256 / 2;
    int*   ssrc     = ws + off;           off += (size_t)N * CAP;
    // contiguous zeroed region (zeroed by prep_kernel blocks 0..41):
    float* colsum   = (float*)(ws + off); off += D;
    float* colsumsq = (float*)(ws + off); off += D;
    int*   counts   = ws + off;           off += N;
    int nzero = 2 * D + N;               // 10512 words

    int nconv = (Mpad * 32) / 256;       // 1256 blocks, 8 elems/thread
    prep_kernel<<<42 + 512 + nconv, 256, 0, stream>>>(
        x, Wl, Wr, (int*)colsum, nzero, Bt, Xbf, N);

    int nMtiles = (N + 63) / 64;         // 157
    int ngemm = nMtiles * 8;             // 1256
    int nscat = (E + N + 255) / 256;     // 665
    gemm_scatter_kernel<<<ngemm + nscat, 256, 0, stream>>>(
        Xbf, Bt, bl, br, ei, counts, ssrc, xlbf, xr, N, E, N, ngemm);

    node_kernel<<<(N + 3) / 4, 256, 0, stream>>>(
        xlbf, xr, att, bias, du, counts, ssrc, (float*)d_out, N);

    bn_reduce_kernel<<<128, 512, 0, stream>>>((const float*)d_out, colsum, colsumsq, N);
    bn_apply_kernel<<<(N * D / 4 + 255) / 256, 256, 0, stream>>>(
        (float*)d_out, colsum, colsumsq, gamma, beta, N);
}

// Round 3
// 143.323 us; speedup vs baseline: 1.1694x; 1.0376x over previous
//
#include <hip/hip_runtime.h>
#include <hip/hip_bf16.h>
#include <math.h>

// N=10000, E=160000, DIN=DOUT=256. edge_index is int32 (verified R4/R5).
#define D 256
#define CAP 128           // per-node edge slots; max degree ~45 for this graph
#define NEG_SLOPE 0.2f
#define BN_EPS 1e-5f
#define NBKT 64           // BN column-sum buckets (39 atomics/address, vs R12's 2500)

typedef __attribute__((ext_vector_type(8))) short bf16x8;
typedef __attribute__((ext_vector_type(8))) unsigned short ushort8;
typedef __attribute__((ext_vector_type(4))) float f32x4;

__device__ inline unsigned short f2bf(float f) {
    union { float f; unsigned u; } v; v.f = f;
    unsigned u = v.u;
    unsigned r = u + 0x7FFFu + ((u >> 16) & 1u);   // RNE
    return (unsigned short)(r >> 16);
}
__device__ inline float bf2f(unsigned short u) {
    union { unsigned u; float f; } v; v.u = ((unsigned)u) << 16; return v.f;
}

// async global->LDS, 16B per lane. LDS dest must be linear (wave base + lane*16);
// swizzle is pre-applied to the GLOBAL layout (m173 pattern: both-sides-or-neither).
__device__ __forceinline__ void gload16(const void* g, void* l) {
    __builtin_amdgcn_global_load_lds(
        (const __attribute__((address_space(1))) unsigned int*)g,
        (__attribute__((address_space(3))) unsigned int*)l,
        16, 0, 0);
}

// ---------------------------------------------------------------------------
// prep: blocks [0,nzb) zero bsum+bsq+counts; [nzb,nzb+512) Bt transpose
// (bf16, XOR-swizzled); [nzb+512,...) X fp32->bf16 (XOR-swizzled, zero-padded
// to Mpad rows so the GEMM staging needs no row guard).
// Swizzle: element index k ^= ((row & 7) << 3) — conflict-free ds_read_b128.
// ---------------------------------------------------------------------------
__global__ void prep_kernel(const float* __restrict__ X,
                            const float* __restrict__ Wl, const float* __restrict__ Wr,
                            int* __restrict__ zero_base, int nzero, int nzb,
                            unsigned short* __restrict__ Bt,
                            unsigned short* __restrict__ Xbf, int N) {
    int b = blockIdx.x;
    if (b < nzb) {
        int idx = b * 256 + threadIdx.x;
        if (idx < nzero) zero_base[idx] = 0;
    } else if (b < nzb + 512) {
        int n = b - nzb;              // 0..511
        int k = threadIdx.x;          // 0..255
        const float* W = (n < 256) ? Wl : Wr;
        int nn = n & 255;
        int ks = k ^ ((n & 7) << 3);  // swizzled element slot
        Bt[(size_t)n * 256 + ks] = f2bf(W[(size_t)k * 256 + nn]);
    } else {
        int idx = (b - nzb - 512) * 256 + threadIdx.x;   // one 16B chunk (8 elems)
        int row = idx >> 5;                        // 0..Mpad-1
        int k0 = (idx & 31) * 8;                   // element base, multiple of 8
        int ks = k0 ^ ((row & 7) << 3);            // swizzled chunk slot
        ushort8 v = {0, 0, 0, 0, 0, 0, 0, 0};
        if (row < N) {
            const float* src = X + (size_t)row * 256 + k0;
            float4 f0 = *(const float4*)(src);
            float4 f1 = *(const float4*)(src + 4);
            v[0] = f2bf(f0.x); v[1] = f2bf(f0.y);
            v[2] = f2bf(f0.z); v[3] = f2bf(f0.w);
            v[4] = f2bf(f1.x); v[5] = f2bf(f1.y);
            v[6] = f2bf(f1.z); v[7] = f2bf(f1.w);
        }
        *(ushort8*)(Xbf + (size_t)row * 256 + ks) = v;   // pad rows -> zeros
    }
}

// ---------------------------------------------------------------------------
// gemm_scatter: blocks [0,ngemm) = 64x64 MFMA GEMM tiles. Staging is pure
// global_load_lds width-16 (no f2bf, no reg round-trip, no LDS writes): both
// Xbf and Bt are pre-converted bf16 with the st-16B XOR swizzle baked into
// their global layout, so linear LDS + swizzled ds_read is conflict-free.
// blocks [ngemm,...) = per-dst edge slot scatter.
// ---------------------------------------------------------------------------
__global__ __launch_bounds__(256) void gemm_scatter_kernel(
    const unsigned short* __restrict__ Xbf, const unsigned short* __restrict__ Bt,
    const float* __restrict__ bl, const float* __restrict__ br,
    const int* __restrict__ ei, int* __restrict__ counts, int* __restrict__ ssrc,
    unsigned short* __restrict__ xlbf, float* __restrict__ xr,
    int M, int E, int N, int ngemm)
{
    if ((int)blockIdx.x >= ngemm) {
        int e = (blockIdx.x - ngemm) * 256 + threadIdx.x;
        if (e < E + N) {
            int src, dst;
            if (e < E) { src = ei[e]; dst = ei[E + e]; }
            else       { src = dst = e - E; }          // self-loop
            int pos = atomicAdd(&counts[dst], 1);
            if (pos < CAP) ssrc[dst * CAP + pos] = src;
        }
        return;
    }

    __shared__ __align__(16) unsigned short As[64 * 128];   // linear, swizzled content
    __shared__ __align__(16) unsigned short Bs[64 * 128];

    const int tid = threadIdx.x;
    const int wave = tid >> 6, lane = tid & 63;
    const int m_l = lane & 15, quad = lane >> 4;
    const int row0 = (blockIdx.x >> 3) * 64;
    const int n0 = (blockIdx.x & 7) * 64;
    const int sw = (m_l & 7) << 3;                  // read-side XOR (elements)

    f32x4 acc[4] = {};

    for (int k0 = 0; k0 < 256; k0 += 128) {
        __syncthreads();
        #pragma unroll
        for (int i = 0; i < 4; i++) {
            int L = (tid + i * 256) * 16;           // LDS byte offset 0..16368
            int r = L >> 8;                         // tile row 0..63
            int cb = L & 255;                       // byte within 128-elem half
            gload16((const char*)Xbf + (size_t)(row0 + r) * 512 + (size_t)k0 * 2 + cb,
                    (char*)As + L);
            gload16((const char*)Bt + (size_t)(n0 + r) * 512 + (size_t)k0 * 2 + cb,
                    (char*)Bs + L);
        }
        __syncthreads();   // compiler drains vmcnt here (m97 pattern)

        #pragma unroll
        for (int kk0 = 0; kk0 < 128; kk0 += 32) {
            int ka = (kk0 + quad * 8) ^ sw;         // swizzled element index
            bf16x8 a = *(const bf16x8*)&As[(wave * 16 + m_l) * 128 + ka];
            #pragma unroll
            for (int c = 0; c < 4; c++) {
                bf16x8 b = *(const bf16x8*)&Bs[(c * 16 + m_l) * 128 + ka];
                acc[c] = __builtin_amdgcn_mfma_f32_16x16x32_bf16(a, b, acc[c], 0, 0, 0);
            }
        }
    }

    const bool isl = (n0 < 256);
    #pragma unroll
    for (int c = 0; c < 4; c++) {
        int col = n0 + c * 16 + m_l;
        int cc = col & 255;
        float bv = isl ? bl[cc] : br[cc];
        #pragma unroll
        for (int r = 0; r < 4; r++) {
            int row = row0 + wave * 16 + quad * 4 + r;
            if (row < M) {
                float v = acc[c][r] + bv;
                if (isl) xlbf[(size_t)row * 256 + cc] = f2bf(v);
                else     xr[(size_t)row * 256 + cc] = v;
            }
        }
    }
}

// ---------------------------------------------------------------------------
// node: 2500 blocks x 4 waves, ONE NODE PER WAVE. Register adjacency + shfl
// addressing (R2 winner). Fused bias+ReLU+dropout AND (new this round) BN
// statistics: block LDS-combines its 4 rows, then ONE atomicAdd pair per
// column into bucket (blockIdx&63) -> 39 atomics/address (R12 lesson: 2500
// same-address atomics = 50 µs; 64 buckets sidesteps it). Removes the
// bn_reduce kernel and its 10 MB re-read of `out`.
// ---------------------------------------------------------------------------
__device__ inline float dot8leaky(const float* f, float4 bA, float4 bB,
                                  float4 aA, float4 aB) {
    float h, s = 0.f;
    h = f[0] + bA.x; h = (h > 0.f) ? h : NEG_SLOPE * h; s += h * aA.x;
    h = f[1] + bA.y; h = (h > 0.f) ? h : NEG_SLOPE * h; s += h * aA.y;
    h = f[2] + bA.z; h = (h > 0.f) ? h : NEG_SLOPE * h; s += h * aA.z;
    h = f[3] + bA.w; h = (h > 0.f) ? h : NEG_SLOPE * h; s += h * aA.w;
    h = f[4] + bB.x; h = (h > 0.f) ? h : NEG_SLOPE * h; s += h * aB.x;
    h = f[5] + bB.y; h = (h > 0.f) ? h : NEG_SLOPE * h; s += h * aB.y;
    h = f[6] + bB.z; h = (h > 0.f) ? h : NEG_SLOPE * h; s += h * aB.z;
    h = f[7] + bB.w; h = (h > 0.f) ? h : NEG_SLOPE * h; s += h * aB.w;
    return s;
}

__global__ __launch_bounds__(256) void node_kernel(
    const unsigned short* __restrict__ xlbf, const float* __restrict__ xr,
    const float* __restrict__ att, const float* __restrict__ bias,
    const float* __restrict__ du, const int* __restrict__ counts,
    const int* __restrict__ ssrc, float* __restrict__ out,
    float* __restrict__ bsum, float* __restrict__ bsq, int N)
{
    __shared__ float ls[4][256];

    const int wave = threadIdx.x >> 6, lane = threadIdx.x & 63;
    const int i = blockIdx.x * 4 + wave;
    const bool valid = (i < N);
    const int hl = lane & 31;
    const int sid = lane >> 5;                  // stream 0 or 1

    int cnt = valid ? counts[i] : 0;
    if (cnt > CAP) cnt = CAP;
    const int start = i * CAP, end = start + cnt;

    // one coalesced load grabs the whole adjacency list
    int srcv = (lane < cnt) ? ssrc[start + lane] : 0;

    const float4 attA = ((const float4*)att)[hl * 2];
    const float4 attB = ((const float4*)att)[hl * 2 + 1];
    const float4 zf4 = {0.f, 0.f, 0.f, 0.f};
    const float4 bA = valid ? ((const float4*)(xr + (size_t)i * D))[hl * 2] : zf4;
    const float4 bB = valid ? ((const float4*)(xr + (size_t)i * D))[hl * 2 + 1] : zf4;

    float m = -INFINITY, lsum = 0.f;
    float acc[8] = {0.f, 0.f, 0.f, 0.f, 0.f, 0.f, 0.f, 0.f};
    const ushort8 z8 = {0, 0, 0, 0, 0, 0, 0, 0};
    const unsigned short* xb = xlbf + hl * 8;

    int e = start + sid;                        // stream edges: e, e+2, e+4, ...

    if (cnt <= 64) {
        // ---- fast path: register adjacency, shfl addressing ----
        ushort8 p0, p1, p2, p3;
        {
            int o = sid;
            int a0 = __shfl(srcv, o);
            int a1 = __shfl(srcv, o + 2);
            int a2 = __shfl(srcv, o + 4);
            int a3 = __shfl(srcv, o + 6);
            p0 = (e     < end) ? *(const ushort8*)(xb + (size_t)a0 * D) : z8;
            p1 = (e + 2 < end) ? *(const ushort8*)(xb + (size_t)a1 * D) : z8;
            p2 = (e + 4 < end) ? *(const ushort8*)(xb + (size_t)a2 * D) : z8;
            p3 = (e + 6 < end) ? *(const ushort8*)(xb + (size_t)a3 * D) : z8;
        }

        while (e < end) {
            ushort8 c0 = p0, c1 = p1, c2 = p2, c3 = p3;
            bool v1 = (e + 2 < end), v2 = (e + 4 < end), v3 = (e + 6 < end);
            int en = e + 8;
            {
                int on = en - start;
                int a0 = __shfl(srcv, on);
                int a1 = __shfl(srcv, on + 2);
                int a2 = __shfl(srcv, on + 4);
                int a3 = __shfl(srcv, on + 6);
                p0 = (en     < end) ? *(const ushort8*)(xb + (size_t)a0 * D) : z8;
                p1 = (en + 2 < end) ? *(const ushort8*)(xb + (size_t)a1 * D) : z8;
                p2 = (en + 4 < end) ? *(const ushort8*)(xb + (size_t)a2 * D) : z8;
                p3 = (en + 6 < end) ? *(const ushort8*)(xb + (size_t)a3 * D) : z8;
            }

            float f0[8], f1[8], f2[8], f3[8];
            #pragma unroll
            for (int k = 0; k < 8; k++) {
                f0[k] = bf2f(c0[k]); f1[k] = bf2f(c1[k]);
                f2[k] = bf2f(c2[k]); f3[k] = bf2f(c3[k]);
            }

            float s0 = dot8leaky(f0, bA, bB, attA, attB);
            float s1 = dot8leaky(f1, bA, bB, attA, attB);
            float s2 = dot8leaky(f2, bA, bB, attA, attB);
            float s3 = dot8leaky(f3, bA, bB, attA, attB);

            #pragma unroll
            for (int off = 1; off < 32; off <<= 1) {    // 5-step, within half-wave
                s0 += __shfl_xor(s0, off);
                s1 += __shfl_xor(s1, off);
                s2 += __shfl_xor(s2, off);
                s3 += __shfl_xor(s3, off);
            }
            if (!v1) s1 = -INFINITY;
            if (!v2) s2 = -INFINITY;
            if (!v3) s3 = -INFINITY;

            float mnew = fmaxf(fmaxf(m, fmaxf(s0, s1)), fmaxf(s2, s3));
            float sc = __expf(m - mnew);                 // exp(-inf-finite)=0, safe
            float e0e = __expf(s0 - mnew);
            float e1e = __expf(s1 - mnew);
            float e2e = __expf(s2 - mnew);
            float e3e = __expf(s3 - mnew);
            lsum = lsum * sc + e0e + e1e + e2e + e3e;
            #pragma unroll
            for (int k = 0; k < 8; k++) {
                acc[k] = acc[k] * sc + e0e * f0[k] + e1e * f1[k]
                                     + e2e * f2[k] + e3e * f3[k];
            }
            m = mnew;
            e = en;
        }
    } else {
        // ---- cold fallback (cnt > 64, impossible for this graph) ----
        ushort8 p0, p1, p2, p3;
        p0 = (e     < end) ? *(const ushort8*)(xb + (size_t)ssrc[e]     * D) : z8;
        p1 = (e + 2 < end) ? *(const ushort8*)(xb + (size_t)ssrc[e + 2] * D) : z8;
        p2 = (e + 4 < end) ? *(const ushort8*)(xb + (size_t)ssrc[e + 4] * D) : z8;
        p3 = (e + 6 < end) ? *(const ushort8*)(xb + (size_t)ssrc[e + 6] * D) : z8;

        while (e < end) {
            ushort8 c0 = p0, c1 = p1, c2 = p2, c3 = p3;
            bool v1 = (e + 2 < end), v2 = (e + 4 < end), v3 = (e + 6 < end);
            int en = e + 8;
            p0 = (en     < end) ? *(const ushort8*)(xb + (size_t)ssrc[en]     * D) : z8;
            p1 = (en + 2 < end) ? *(const ushort8*)(xb + (size_t)ssrc[en + 2] * D) : z8;
            p2 = (en + 4 < end) ? *(const ushort8*)(xb + (size_t)ssrc[en + 4] * D) : z8;
            p3 = (en + 6 < end) ? *(const ushort8*)(xb + (size_t)ssrc[en + 6] * D) : z8;

            float f0[8], f1[8], f2[8], f3[8];
            #pragma unroll
            for (int k = 0; k < 8; k++) {
                f0[k] = bf2f(c0[k]); f1[k] = bf2f(c1[k]);
                f2[k] = bf2f(c2[k]); f3[k] = bf2f(c3[k]);
            }

            float s0 = dot8leaky(f0, bA, bB, attA, attB);
            float s1 = dot8leaky(f1, bA, bB, attA, attB);
            float s2 = dot8leaky(f2, bA, bB, attA, attB);
            float s3 = dot8leaky(f3, bA, bB, attA, attB);

            #pragma unroll
            for (int off = 1; off < 32; off <<= 1) {
                s0 += __shfl_xor(s0, off);
                s1 += __shfl_xor(s1, off);
                s2 += __shfl_xor(s2, off);
                s3 += __shfl_xor(s3, off);
            }
            if (!v1) s1 = -INFINITY;
            if (!v2) s2 = -INFINITY;
            if (!v3) s3 = -INFINITY;

            float mnew = fmaxf(fmaxf(m, fmaxf(s0, s1)), fmaxf(s2, s3));
            float sc = __expf(m - mnew);
            float e0e = __expf(s0 - mnew);
            float e1e = __expf(s1 - mnew);
            float e2e = __expf(s2 - mnew);
            float e3e = __expf(s3 - mnew);
            lsum = lsum * sc + e0e + e1e + e2e + e3e;
            #pragma unroll
            for (int k = 0; k < 8; k++) {
                acc[k] = acc[k] * sc + e0e * f0[k] + e1e * f1[k]
                                     + e2e * f2[k] + e3e * f3[k];
            }
            m = mnew;
            e = en;
        }
    }

    // combine the two half-wave streams (guard -inf - -inf = nan; stream 1 may
    // be empty for degree-1 nodes, stream 0 always has the self-loop)
    {
        float mO = __shfl_xor(m, 32);
        float lO = __shfl_xor(lsum, 32);
        float accO[8];
        #pragma unroll
        for (int k = 0; k < 8; k++) accO[k] = __shfl_xor(acc[k], 32);
        float mn = fmaxf(m, mO);
        float wS = (m  == -INFINITY) ? 0.f : __expf(m - mn);
        float wO = (mO == -INFINITY) ? 0.f : __expf(mO - mn);
        lsum = lsum * wS + lO * wO;
        #pragma unroll
        for (int k = 0; k < 8; k++) acc[k] = acc[k] * wS + accO[k] * wO;
    }

    // epilogue: bias+ReLU+dropout, store, and stage values for BN stats
    float ov[8];
    if (lane < 32) {
        if (valid) {
            float inv = 1.f / lsum;
            float4 biA = ((const float4*)bias)[hl * 2];
            float4 biB = ((const float4*)bias)[hl * 2 + 1];
            float4 uA = ((const float4*)(du + (size_t)i * D))[hl * 2];
            float4 uB = ((const float4*)(du + (size_t)i * D))[hl * 2 + 1];
            float4 oA, oB;
            oA.x = fmaxf(acc[0] * inv + biA.x, 0.f); oA.x = (uA.x >= 0.5f) ? 2.f * oA.x : 0.f;
            oA.y = fmaxf(acc[1] * inv + biA.y, 0.f); oA.y = (uA.y >= 0.5f) ? 2.f * oA.y : 0.f;
            oA.z = fmaxf(acc[2] * inv + biA.z, 0.f); oA.z = (uA.z >= 0.5f) ? 2.f * oA.z : 0.f;
            oA.w = fmaxf(acc[3] * inv + biA.w, 0.f); oA.w = (uA.w >= 0.5f) ? 2.f * oA.w : 0.f;
            oB.x = fmaxf(acc[4] * inv + biB.x, 0.f); oB.x = (uB.x >= 0.5f) ? 2.f * oB.x : 0.f;
            oB.y = fmaxf(acc[5] * inv + biB.y, 0.f); oB.y = (uB.y >= 0.5f) ? 2.f * oB.y : 0.f;
            oB.z = fmaxf(acc[6] * inv + biB.z, 0.f); oB.z = (uB.z >= 0.5f) ? 2.f * oB.z : 0.f;
            oB.w = fmaxf(acc[7] * inv + biB.w, 0.f); oB.w = (uB.w >= 0.5f) ? 2.f * oB.w : 0.f;
            ((float4*)(out + (size_t)i * D))[hl * 2] = oA;
            ((float4*)(out + (size_t)i * D))[hl * 2 + 1] = oB;
            ov[0] = oA.x; ov[1] = oA.y; ov[2] = oA.z; ov[3] = oA.w;
            ov[4] = oB.x; ov[5] = oB.y; ov[6] = oB.z; ov[7] = oB.w;
        } else {
            #pragma unroll
            for (int k = 0; k < 8; k++) ov[k] = 0.f;
        }
        #pragma unroll
        for (int k = 0; k < 8; k++) ls[wave][hl * 8 + k] = ov[k];
    }
    __syncthreads();

    // per-block column reduction over the 4 rows, one atomic pair per column
    {
        int t = threadIdx.x;
        float s = 0.f, s2 = 0.f;
        #pragma unroll
        for (int w = 0; w < 4; w++) {
            float v = ls[w][t];
            s += v; s2 += v * v;
        }
        int bkt = (blockIdx.x & (NBKT - 1)) * 256 + t;
        atomicAdd(&bsum[bkt], s);
        atomicAdd(&bsq[bkt], s2);
    }
}

// ---------------------------------------------------------------------------
// bn_apply: 256 blocks. Prologue reduces the 64 buckets (coalesced, LDS-cached
// scale/shift), then one FMA per element over out in place.
// ---------------------------------------------------------------------------
__global__ __launch_bounds__(256) void bn_apply_kernel(
    float* __restrict__ out,
    const float* __restrict__ bsum, const float* __restrict__ bsq,
    const float* __restrict__ gamma, const float* __restrict__ beta, int N)
{
    __shared__ float scaleL[256], shiftL[256];
    const int t = threadIdx.x;
    float s = 0.f, s2 = 0.f;
    #pragma unroll 8
    for (int b = 0; b < NBKT; b++) {
        s += bsum[b * 256 + t];
        s2 += bsq[b * 256 + t];
    }
    float invN = 1.f / (float)N;
    float mean = s * invN;
    float var = s2 * invN - mean * mean;
    float rs = rsqrtf(var + BN_EPS);
    float sc = gamma[t] * rs;
    scaleL[t] = sc;
    shiftL[t] = beta[t] - mean * sc;
    __syncthreads();

    const int c4 = t & 63;                       // float4 slot within row
    float4 scv, shv;
    scv.x = scaleL[c4 * 4];     shv.x = shiftL[c4 * 4];
    scv.y = scaleL[c4 * 4 + 1]; shv.y = shiftL[c4 * 4 + 1];
    scv.z = scaleL[c4 * 4 + 2]; shv.z = shiftL[c4 * 4 + 2];
    scv.w = scaleL[c4 * 4 + 3]; shv.w = shiftL[c4 * 4 + 3];

    for (int row = blockIdx.x * 4 + (t >> 6); row < N; row += gridDim.x * 4) {
        float4 v = ((float4*)(out + (size_t)row * D))[c4];
        v.x = v.x * scv.x + shv.x;
        v.y = v.y * scv.y + shv.y;
        v.z = v.z * scv.z + shv.z;
        v.w = v.w * scv.w + shv.w;
        ((float4*)(out + (size_t)row * D))[c4] = v;
    }
}

// ---------------------------------------------------------------------------
extern "C" void kernel_launch(void* const* d_in, const int* in_sizes, int n_in,
                              void* d_out, int out_size, void* d_ws, size_t ws_size,
                              hipStream_t stream) {
    const float* x     = (const float*)d_in[0];
    const int*   ei    = (const int*)d_in[1];
    const float* Wl    = (const float*)d_in[2];
    const float* bl    = (const float*)d_in[3];
    const float* Wr    = (const float*)d_in[4];
    const float* br    = (const float*)d_in[5];
    const float* att   = (const float*)d_in[6];
    const float* bias  = (const float*)d_in[7];
    const float* gamma = (const float*)d_in[8];
    const float* beta  = (const float*)d_in[9];
    const float* du    = (const float*)d_in[10];

    const int N = in_sizes[0] / D;       // 10000
    const int E = in_sizes[1] / 2;       // 160000
    const int Mpad = (N + 63) & ~63;     // 10048: zero-padded rows for guard-free staging

    // workspace layout (4-byte word units)
    int* ws = (int*)d_ws;
    size_t off = 0;
    float* xr       = (float*)(ws + off); off += (size_t)N * D;
    unsigned short* xlbf = (unsigned short*)(ws + off); off += (size_t)N * D / 2;
    unsigned short* Xbf  = (unsigned short*)(ws + off); off += (size_t)Mpad * D / 2;
    unsigned short* Bt   = (unsigned short*)(ws + off); off += 512 * 256 / 2;
    int*   ssrc     = ws + off;           off += (size_t)N * CAP;
    // contiguous zeroed region (zeroed by prep_kernel blocks [0,nzb)):
    float* bsum     = (float*)(ws + off); off += NBKT * 256;
    float* bsq      = (float*)(ws + off); off += NBKT * 256;
    int*   counts   = ws + off;           off += N;
    int nzero = 2 * NBKT * 256 + N;      // 42768 words
    int nzb = (nzero + 255) / 256;       // 168 zero blocks

    int nconv = (Mpad * 32) / 256;       // 1256 blocks, 8 elems/thread
    prep_kernel<<<nzb + 512 + nconv, 256, 0, stream>>>(
        x, Wl, Wr, (int*)bsum, nzero, nzb, Bt, Xbf, N);

    int nMtiles = (N + 63) / 64;         // 157
    int ngemm = nMtiles * 8;             // 1256
    int nscat = (E + N + 255) / 256;     // 665
    gemm_scatter_kernel<<<ngemm + nscat, 256, 0, stream>>>(
        Xbf, Bt, bl, br, ei, counts, ssrc, xlbf, xr, N, E, N, ngemm);

    node_kernel<<<(N + 3) / 4, 256, 0, stream>>>(
        xlbf, xr, att, bias, du, counts, ssrc, (float*)d_out, bsum, bsq, N);

    bn_apply_kernel<<<256, 256, 0, stream>>>(
        (float*)d_out, bsum, bsq, gamma, beta, N);
}

// Round 4
// 143.064 us; speedup vs baseline: 1.1716x; 1.0018x over previous
//
#include <hip/hip_runtime.h>
#include <hip/hip_bf16.h>
#include <math.h>

// N=10000, E=160000, DIN=DOUT=256. edge_index is int32 (verified R4/R5).
#define D 256
#define CAP 128           // per-node edge slots; max degree ~45 for this graph
#define NEG_SLOPE 0.2f
#define BN_EPS 1e-5f
#define NBKT 64           // BN column-sum buckets (39 atomics/address, vs R12's 2500)

typedef __attribute__((ext_vector_type(8))) short bf16x8;
typedef __attribute__((ext_vector_type(8))) unsigned short ushort8;
typedef __attribute__((ext_vector_type(4))) float f32x4;

__device__ inline unsigned short f2bf(float f) {
    union { float f; unsigned u; } v; v.f = f;
    unsigned u = v.u;
    unsigned r = u + 0x7FFFu + ((u >> 16) & 1u);   // RNE
    return (unsigned short)(r >> 16);
}
__device__ inline float bf2f(unsigned short u) {
    union { unsigned u; float f; } v; v.u = ((unsigned)u) << 16; return v.f;
}

// async global->LDS, 16B per lane. LDS dest must be linear (wave base + lane*16);
// swizzle is pre-applied to the GLOBAL layout (m173 pattern: both-sides-or-neither).
__device__ __forceinline__ void gload16(const void* g, void* l) {
    __builtin_amdgcn_global_load_lds(
        (const __attribute__((address_space(1))) unsigned int*)g,
        (__attribute__((address_space(3))) unsigned int*)l,
        16, 0, 0);
}

// ---------------------------------------------------------------------------
// prep: blocks [0,nzb) zero bsum+bsq+counts; [nzb,nzb+512) Bt transpose
// (bf16, XOR-swizzled); [nzb+512,...) X fp32->bf16 (XOR-swizzled, zero-padded
// to Mpad rows so the GEMM staging needs no row guard).
// Swizzle: element index k ^= ((row & 7) << 3) — conflict-free ds_read_b128.
// ---------------------------------------------------------------------------
__global__ void prep_kernel(const float* __restrict__ X,
                            const float* __restrict__ Wl, const float* __restrict__ Wr,
                            int* __restrict__ zero_base, int nzero, int nzb,
                            unsigned short* __restrict__ Bt,
                            unsigned short* __restrict__ Xbf, int N) {
    int b = blockIdx.x;
    if (b < nzb) {
        int idx = b * 256 + threadIdx.x;
        if (idx < nzero) zero_base[idx] = 0;
    } else if (b < nzb + 512) {
        int n = b - nzb;              // 0..511
        int k = threadIdx.x;          // 0..255
        const float* W = (n < 256) ? Wl : Wr;
        int nn = n & 255;
        int ks = k ^ ((n & 7) << 3);  // swizzled element slot
        Bt[(size_t)n * 256 + ks] = f2bf(W[(size_t)k * 256 + nn]);
    } else {
        int idx = (b - nzb - 512) * 256 + threadIdx.x;   // one 16B chunk (8 elems)
        int row = idx >> 5;                        // 0..Mpad-1
        int k0 = (idx & 31) * 8;                   // element base, multiple of 8
        int ks = k0 ^ ((row & 7) << 3);            // swizzled chunk slot
        ushort8 v = {0, 0, 0, 0, 0, 0, 0, 0};
        if (row < N) {
            const float* src = X + (size_t)row * 256 + k0;
            float4 f0 = *(const float4*)(src);
            float4 f1 = *(const float4*)(src + 4);
            v[0] = f2bf(f0.x); v[1] = f2bf(f0.y);
            v[2] = f2bf(f0.z); v[3] = f2bf(f0.w);
            v[4] = f2bf(f1.x); v[5] = f2bf(f1.y);
            v[6] = f2bf(f1.z); v[7] = f2bf(f1.w);
        }
        *(ushort8*)(Xbf + (size_t)row * 256 + ks) = v;   // pad rows -> zeros
    }
}

// ---------------------------------------------------------------------------
// gemm_scatter: blocks [0,ngemm) = 64x64 MFMA GEMM tiles with XCD-affinity
// swizzle (T1): all 8 col-tiles of one A row-tile map to the SAME XCD
// (r = (b&7) + 8*(b>>6), c = (b>>3)&7; dispatcher round-robins b%8 across
// XCDs), so the A-tile is fetched from L3 once and L2-hit 7x, instead of
// being re-fetched by 8 different XCDs. Guarded: r >= nMtiles early-exits.
// Staging is pure global_load_lds width-16 into linear LDS (swizzle baked
// into the global layout). blocks [ngemm,...) = per-dst edge slot scatter.
// ---------------------------------------------------------------------------
__global__ __launch_bounds__(256) void gemm_scatter_kernel(
    const unsigned short* __restrict__ Xbf, const unsigned short* __restrict__ Bt,
    const float* __restrict__ bl, const float* __restrict__ br,
    const int* __restrict__ ei, int* __restrict__ counts, int* __restrict__ ssrc,
    unsigned short* __restrict__ xlbf, float* __restrict__ xr,
    int M, int E, int N, int ngemm, int nMtiles)
{
    if ((int)blockIdx.x >= ngemm) {
        int e = (blockIdx.x - ngemm) * 256 + threadIdx.x;
        if (e < E + N) {
            int src, dst;
            if (e < E) { src = ei[e]; dst = ei[E + e]; }
            else       { src = dst = e - E; }          // self-loop
            int pos = atomicAdd(&counts[dst], 1);
            if (pos < CAP) ssrc[dst * CAP + pos] = src;
        }
        return;
    }

    // XCD-affinity decomposition (dispatch b -> XCD b%8)
    const int b = blockIdx.x;
    const int r = (b & 7) + 8 * (b >> 6);           // row-tile: constant b%8 across c
    const int c = (b >> 3) & 7;                     // col-tile 0..7
    if (r >= nMtiles) return;                       // guard (before any barrier)

    __shared__ __align__(16) unsigned short As[64 * 128];   // linear, swizzled content
    __shared__ __align__(16) unsigned short Bs[64 * 128];

    const int tid = threadIdx.x;
    const int wave = tid >> 6, lane = tid & 63;
    const int m_l = lane & 15, quad = lane >> 4;
    const int row0 = r * 64;
    const int n0 = c * 64;
    const int sw = (m_l & 7) << 3;                  // read-side XOR (elements)

    f32x4 acc[4] = {};

    for (int k0 = 0; k0 < 256; k0 += 128) {
        __syncthreads();
        #pragma unroll
        for (int i = 0; i < 4; i++) {
            int L = (tid + i * 256) * 16;           // LDS byte offset 0..16368
            int rr = L >> 8;                        // tile row 0..63
            int cb = L & 255;                       // byte within 128-elem half
            gload16((const char*)Xbf + (size_t)(row0 + rr) * 512 + (size_t)k0 * 2 + cb,
                    (char*)As + L);
            gload16((const char*)Bt + (size_t)(n0 + rr) * 512 + (size_t)k0 * 2 + cb,
                    (char*)Bs + L);
        }
        __syncthreads();   // compiler drains vmcnt here (m97 pattern)

        #pragma unroll
        for (int kk0 = 0; kk0 < 128; kk0 += 32) {
            int ka = (kk0 + quad * 8) ^ sw;         // swizzled element index
            bf16x8 a = *(const bf16x8*)&As[(wave * 16 + m_l) * 128 + ka];
            #pragma unroll
            for (int cc = 0; cc < 4; cc++) {
                bf16x8 bv = *(const bf16x8*)&Bs[(cc * 16 + m_l) * 128 + ka];
                acc[cc] = __builtin_amdgcn_mfma_f32_16x16x32_bf16(a, bv, acc[cc], 0, 0, 0);
            }
        }
    }

    const bool isl = (n0 < 256);
    #pragma unroll
    for (int cc = 0; cc < 4; cc++) {
        int col = n0 + cc * 16 + m_l;
        int col8 = col & 255;
        float bv = isl ? bl[col8] : br[col8];
        #pragma unroll
        for (int rr = 0; rr < 4; rr++) {
            int row = row0 + wave * 16 + quad * 4 + rr;
            if (row < M) {
                float v = acc[cc][rr] + bv;
                if (isl) xlbf[(size_t)row * 256 + col8] = f2bf(v);
                else     xr[(size_t)row * 256 + col8] = v;
            }
        }
    }
}

// ---------------------------------------------------------------------------
// node: 2500 blocks x 4 waves, ONE NODE PER WAVE. Register adjacency + shfl
// addressing (R2 winner). NEW this round: ssrc vector load is UNCONDITIONAL
// (no longer predicated on counts[i] -> counts/ssrc/xr all issue in parallel,
// cutting one serial L2 round-trip per wave; stale slots only feed
// exec-masked-off gathers) and the dropout row load is hoisted above the
// edge loop so its latency hides under the gathers. Fused bias+ReLU+dropout
// + BN bucket stats (64 buckets, 39 atomics/address — R12 lesson).
// ---------------------------------------------------------------------------
__device__ inline float dot8leaky(const float* f, float4 bA, float4 bB,
                                  float4 aA, float4 aB) {
    float h, s = 0.f;
    h = f[0] + bA.x; h = (h > 0.f) ? h : NEG_SLOPE * h; s += h * aA.x;
    h = f[1] + bA.y; h = (h > 0.f) ? h : NEG_SLOPE * h; s += h * aA.y;
    h = f[2] + bA.z; h = (h > 0.f) ? h : NEG_SLOPE * h; s += h * aA.z;
    h = f[3] + bA.w; h = (h > 0.f) ? h : NEG_SLOPE * h; s += h * aA.w;
    h = f[4] + bB.x; h = (h > 0.f) ? h : NEG_SLOPE * h; s += h * aB.x;
    h = f[5] + bB.y; h = (h > 0.f) ? h : NEG_SLOPE * h; s += h * aB.y;
    h = f[6] + bB.z; h = (h > 0.f) ? h : NEG_SLOPE * h; s += h * aB.z;
    h = f[7] + bB.w; h = (h > 0.f) ? h : NEG_SLOPE * h; s += h * aB.w;
    return s;
}

__global__ __launch_bounds__(256) void node_kernel(
    const unsigned short* __restrict__ xlbf, const float* __restrict__ xr,
    const float* __restrict__ att, const float* __restrict__ bias,
    const float* __restrict__ du, const int* __restrict__ counts,
    const int* __restrict__ ssrc, float* __restrict__ out,
    float* __restrict__ bsum, float* __restrict__ bsq, int N)
{
    __shared__ float ls[4][256];

    const int wave = threadIdx.x >> 6, lane = threadIdx.x & 63;
    const int i = blockIdx.x * 4 + wave;
    const bool valid = (i < N);
    const int hl = lane & 31;
    const int sid = lane >> 5;                  // stream 0 or 1

    const int start = i * CAP;

    // issue all independent loads together: counts, adjacency, xr row, du row
    int cnt = valid ? counts[i] : 0;
    int srcv = valid ? ssrc[start + lane] : 0;   // NOT gated on cnt (poison slots
                                                 // only feed exec-masked loads)
    const float4 zf4 = {0.f, 0.f, 0.f, 0.f};
    const float4 bA = valid ? ((const float4*)(xr + (size_t)i * D))[hl * 2] : zf4;
    const float4 bB = valid ? ((const float4*)(xr + (size_t)i * D))[hl * 2 + 1] : zf4;
    float4 uA = zf4, uB = zf4;
    if (valid && lane < 32) {
        uA = ((const float4*)(du + (size_t)i * D))[hl * 2];
        uB = ((const float4*)(du + (size_t)i * D))[hl * 2 + 1];
    }

    const float4 attA = ((const float4*)att)[hl * 2];
    const float4 attB = ((const float4*)att)[hl * 2 + 1];

    if (cnt > CAP) cnt = CAP;
    const int end = start + cnt;

    float m = -INFINITY, lsum = 0.f;
    float acc[8] = {0.f, 0.f, 0.f, 0.f, 0.f, 0.f, 0.f, 0.f};
    const ushort8 z8 = {0, 0, 0, 0, 0, 0, 0, 0};
    const unsigned short* xb = xlbf + hl * 8;

    int e = start + sid;                        // stream edges: e, e+2, e+4, ...

    if (cnt <= 64) {
        // ---- fast path: register adjacency, shfl addressing ----
        ushort8 p0, p1, p2, p3;
        {
            int o = sid;
            int a0 = __shfl(srcv, o);
            int a1 = __shfl(srcv, o + 2);
            int a2 = __shfl(srcv, o + 4);
            int a3 = __shfl(srcv, o + 6);
            p0 = (e     < end) ? *(const ushort8*)(xb + (size_t)a0 * D) : z8;
            p1 = (e + 2 < end) ? *(const ushort8*)(xb + (size_t)a1 * D) : z8;
            p2 = (e + 4 < end) ? *(const ushort8*)(xb + (size_t)a2 * D) : z8;
            p3 = (e + 6 < end) ? *(const ushort8*)(xb + (size_t)a3 * D) : z8;
        }

        while (e < end) {
            ushort8 c0 = p0, c1 = p1, c2 = p2, c3 = p3;
            bool v1 = (e + 2 < end), v2 = (e + 4 < end), v3 = (e + 6 < end);
            int en = e + 8;
            {
                int on = en - start;
                int a0 = __shfl(srcv, on);
                int a1 = __shfl(srcv, on + 2);
                int a2 = __shfl(srcv, on + 4);
                int a3 = __shfl(srcv, on + 6);
                p0 = (en     < end) ? *(const ushort8*)(xb + (size_t)a0 * D) : z8;
                p1 = (en + 2 < end) ? *(const ushort8*)(xb + (size_t)a1 * D) : z8;
                p2 = (en + 4 < end) ? *(const ushort8*)(xb + (size_t)a2 * D) : z8;
                p3 = (en + 6 < end) ? *(const ushort8*)(xb + (size_t)a3 * D) : z8;
            }

            float f0[8], f1[8], f2[8], f3[8];
            #pragma unroll
            for (int k = 0; k < 8; k++) {
                f0[k] = bf2f(c0[k]); f1[k] = bf2f(c1[k]);
                f2[k] = bf2f(c2[k]); f3[k] = bf2f(c3[k]);
            }

            float s0 = dot8leaky(f0, bA, bB, attA, attB);
            float s1 = dot8leaky(f1, bA, bB, attA, attB);
            float s2 = dot8leaky(f2, bA, bB, attA, attB);
            float s3 = dot8leaky(f3, bA, bB, attA, attB);

            #pragma unroll
            for (int off = 1; off < 32; off <<= 1) {    // 5-step, within half-wave
                s0 += __shfl_xor(s0, off);
                s1 += __shfl_xor(s1, off);
                s2 += __shfl_xor(s2, off);
                s3 += __shfl_xor(s3, off);
            }
            if (!v1) s1 = -INFINITY;
            if (!v2) s2 = -INFINITY;
            if (!v3) s3 = -INFINITY;

            float mnew = fmaxf(fmaxf(m, fmaxf(s0, s1)), fmaxf(s2, s3));
            float sc = __expf(m - mnew);                 // exp(-inf-finite)=0, safe
            float e0e = __expf(s0 - mnew);
            float e1e = __expf(s1 - mnew);
            float e2e = __expf(s2 - mnew);
            float e3e = __expf(s3 - mnew);
            lsum = lsum * sc + e0e + e1e + e2e + e3e;
            #pragma unroll
            for (int k = 0; k < 8; k++) {
                acc[k] = acc[k] * sc + e0e * f0[k] + e1e * f1[k]
                                     + e2e * f2[k] + e3e * f3[k];
            }
            m = mnew;
            e = en;
        }
    } else {
        // ---- cold fallback (cnt > 64, impossible for this graph) ----
        ushort8 p0, p1, p2, p3;
        p0 = (e     < end) ? *(const ushort8*)(xb + (size_t)ssrc[e]     * D) : z8;
        p1 = (e + 2 < end) ? *(const ushort8*)(xb + (size_t)ssrc[e + 2] * D) : z8;
        p2 = (e + 4 < end) ? *(const ushort8*)(xb + (size_t)ssrc[e + 4] * D) : z8;
        p3 = (e + 6 < end) ? *(const ushort8*)(xb + (size_t)ssrc[e + 6] * D) : z8;

        while (e < end) {
            ushort8 c0 = p0, c1 = p1, c2 = p2, c3 = p3;
            bool v1 = (e + 2 < end), v2 = (e + 4 < end), v3 = (e + 6 < end);
            int en = e + 8;
            p0 = (en     < end) ? *(const ushort8*)(xb + (size_t)ssrc[en]     * D) : z8;
            p1 = (en + 2 < end) ? *(const ushort8*)(xb + (size_t)ssrc[en + 2] * D) : z8;
            p2 = (en + 4 < end) ? *(const ushort8*)(xb + (size_t)ssrc[en + 4] * D) : z8;
            p3 = (en + 6 < end) ? *(const ushort8*)(xb + (size_t)ssrc[en + 6] * D) : z8;

            float f0[8], f1[8], f2[8], f3[8];
            #pragma unroll
            for (int k = 0; k < 8; k++) {
                f0[k] = bf2f(c0[k]); f1[k] = bf2f(c1[k]);
                f2[k] = bf2f(c2[k]); f3[k] = bf2f(c3[k]);
            }

            float s0 = dot8leaky(f0, bA, bB, attA, attB);
            float s1 = dot8leaky(f1, bA, bB, attA, attB);
            float s2 = dot8leaky(f2, bA, bB, attA, attB);
            float s3 = dot8leaky(f3, bA, bB, attA, attB);

            #pragma unroll
            for (int off = 1; off < 32; off <<= 1) {
                s0 += __shfl_xor(s0, off);
                s1 += __shfl_xor(s1, off);
                s2 += __shfl_xor(s2, off);
                s3 += __shfl_xor(s3, off);
            }
            if (!v1) s1 = -INFINITY;
            if (!v2) s2 = -INFINITY;
            if (!v3) s3 = -INFINITY;

            float mnew = fmaxf(fmaxf(m, fmaxf(s0, s1)), fmaxf(s2, s3));
            float sc = __expf(m - mnew);
            float e0e = __expf(s0 - mnew);
            float e1e = __expf(s1 - mnew);
            float e2e = __expf(s2 - mnew);
            float e3e = __expf(s3 - mnew);
            lsum = lsum * sc + e0e + e1e + e2e + e3e;
            #pragma unroll
            for (int k = 0; k < 8; k++) {
                acc[k] = acc[k] * sc + e0e * f0[k] + e1e * f1[k]
                                     + e2e * f2[k] + e3e * f3[k];
            }
            m = mnew;
            e = en;
        }
    }

    // combine the two half-wave streams (guard -inf - -inf = nan; stream 1 may
    // be empty for degree-1 nodes, stream 0 always has the self-loop)
    {
        float mO = __shfl_xor(m, 32);
        float lO = __shfl_xor(lsum, 32);
        float accO[8];
        #pragma unroll
        for (int k = 0; k < 8; k++) accO[k] = __shfl_xor(acc[k], 32);
        float mn = fmaxf(m, mO);
        float wS = (m  == -INFINITY) ? 0.f : __expf(m - mn);
        float wO = (mO == -INFINITY) ? 0.f : __expf(mO - mn);
        lsum = lsum * wS + lO * wO;
        #pragma unroll
        for (int k = 0; k < 8; k++) acc[k] = acc[k] * wS + accO[k] * wO;
    }

    // epilogue: bias+ReLU+dropout, store, and stage values for BN stats
    float ov[8];
    if (lane < 32) {
        if (valid) {
            float inv = 1.f / lsum;
            float4 biA = ((const float4*)bias)[hl * 2];
            float4 biB = ((const float4*)bias)[hl * 2 + 1];
            float4 oA, oB;
            oA.x = fmaxf(acc[0] * inv + biA.x, 0.f); oA.x = (uA.x >= 0.5f) ? 2.f * oA.x : 0.f;
            oA.y = fmaxf(acc[1] * inv + biA.y, 0.f); oA.y = (uA.y >= 0.5f) ? 2.f * oA.y : 0.f;
            oA.z = fmaxf(acc[2] * inv + biA.z, 0.f); oA.z = (uA.z >= 0.5f) ? 2.f * oA.z : 0.f;
            oA.w = fmaxf(acc[3] * inv + biA.w, 0.f); oA.w = (uA.w >= 0.5f) ? 2.f * oA.w : 0.f;
            oB.x = fmaxf(acc[4] * inv + biB.x, 0.f); oB.x = (uB.x >= 0.5f) ? 2.f * oB.x : 0.f;
            oB.y = fmaxf(acc[5] * inv + biB.y, 0.f); oB.y = (uB.y >= 0.5f) ? 2.f * oB.y : 0.f;
            oB.z = fmaxf(acc[6] * inv + biB.z, 0.f); oB.z = (uB.z >= 0.5f) ? 2.f * oB.z : 0.f;
            oB.w = fmaxf(acc[7] * inv + biB.w, 0.f); oB.w = (uB.w >= 0.5f) ? 2.f * oB.w : 0.f;
            ((float4*)(out + (size_t)i * D))[hl * 2] = oA;
            ((float4*)(out + (size_t)i * D))[hl * 2 + 1] = oB;
            ov[0] = oA.x; ov[1] = oA.y; ov[2] = oA.z; ov[3] = oA.w;
            ov[4] = oB.x; ov[5] = oB.y; ov[6] = oB.z; ov[7] = oB.w;
        } else {
            #pragma unroll
            for (int k = 0; k < 8; k++) ov[k] = 0.f;
        }
        #pragma unroll
        for (int k = 0; k < 8; k++) ls[wave][hl * 8 + k] = ov[k];
    }
    __syncthreads();

    // per-block column reduction over the 4 rows, one atomic pair per column
    {
        int t = threadIdx.x;
        float s = 0.f, s2 = 0.f;
        #pragma unroll
        for (int w = 0; w < 4; w++) {
            float v = ls[w][t];
            s += v; s2 += v * v;
        }
        int bkt = (blockIdx.x & (NBKT - 1)) * 256 + t;
        atomicAdd(&bsum[bkt], s);
        atomicAdd(&bsq[bkt], s2);
    }
}

// ---------------------------------------------------------------------------
// bn_apply: 256 blocks. Prologue reduces the 64 buckets (coalesced, LDS-cached
// scale/shift), then one FMA per element over out in place.
// ---------------------------------------------------------------------------
__global__ __launch_bounds__(256) void bn_apply_kernel(
    float* __restrict__ out,
    const float* __restrict__ bsum, const float* __restrict__ bsq,
    const float* __restrict__ gamma, const float* __restrict__ beta, int N)
{
    __shared__ float scaleL[256], shiftL[256];
    const int t = threadIdx.x;
    float s = 0.f, s2 = 0.f;
    #pragma unroll 8
    for (int b = 0; b < NBKT; b++) {
        s += bsum[b * 256 + t];
        s2 += bsq[b * 256 + t];
    }
    float invN = 1.f / (float)N;
    float mean = s * invN;
    float var = s2 * invN - mean * mean;
    float rs = rsqrtf(var + BN_EPS);
    float sc = gamma[t] * rs;
    scaleL[t] = sc;
    shiftL[t] = beta[t] - mean * sc;
    __syncthreads();

    const int c4 = t & 63;                       // float4 slot within row
    float4 scv, shv;
    scv.x = scaleL[c4 * 4];     shv.x = shiftL[c4 * 4];
    scv.y = scaleL[c4 * 4 + 1]; shv.y = shiftL[c4 * 4 + 1];
    scv.z = scaleL[c4 * 4 + 2]; shv.z = shiftL[c4 * 4 + 2];
    scv.w = scaleL[c4 * 4 + 3]; shv.w = shiftL[c4 * 4 + 3];

    for (int row = blockIdx.x * 4 + (t >> 6); row < N; row += gridDim.x * 4) {
        float4 v = ((float4*)(out + (size_t)row * D))[c4];
        v.x = v.x * scv.x + shv.x;
        v.y = v.y * scv.y + shv.y;
        v.z = v.z * scv.z + shv.z;
        v.w = v.w * scv.w + shv.w;
        ((float4*)(out + (size_t)row * D))[c4] = v;
    }
}

// ---------------------------------------------------------------------------
extern "C" void kernel_launch(void* const* d_in, const int* in_sizes, int n_in,
                              void* d_out, int out_size, void* d_ws, size_t ws_size,
                              hipStream_t stream) {
    const float* x     = (const float*)d_in[0];
    const int*   ei    = (const int*)d_in[1];
    const float* Wl    = (const float*)d_in[2];
    const float* bl    = (const float*)d_in[3];
    const float* Wr    = (const float*)d_in[4];
    const float* br    = (const float*)d_in[5];
    const float* att   = (const float*)d_in[6];
    const float* bias  = (const float*)d_in[7];
    const float* gamma = (const float*)d_in[8];
    const float* beta  = (const float*)d_in[9];
    const float* du    = (const float*)d_in[10];

    const int N = in_sizes[0] / D;       // 10000
    const int E = in_sizes[1] / 2;       // 160000
    const int Mpad = (N + 63) & ~63;     // 10048: zero-padded rows for guard-free staging

    // workspace layout (4-byte word units)
    int* ws = (int*)d_ws;
    size_t off = 0;
    float* xr       = (float*)(ws + off); off += (size_t)N * D;
    unsigned short* xlbf = (unsigned short*)(ws + off); off += (size_t)N * D / 2;
    unsigned short* Xbf  = (unsigned short*)(ws + off); off += (size_t)Mpad * D / 2;
    unsigned short* Bt   = (unsigned short*)(ws + off); off += 512 * 256 / 2;
    int*   ssrc     = ws + off;           off += (size_t)N * CAP;
    // contiguous zeroed region (zeroed by prep_kernel blocks [0,nzb)):
    float* bsum     = (float*)(ws + off); off += NBKT * 256;
    float* bsq      = (float*)(ws + off); off += NBKT * 256;
    int*   counts   = ws + off;           off += N;
    int nzero = 2 * NBKT * 256 + N;      // 42768 words
    int nzb = (nzero + 255) / 256;       // 168 zero blocks

    int nconv = (Mpad * 32) / 256;       // 1256 blocks, 8 elems/thread
    prep_kernel<<<nzb + 512 + nconv, 256, 0, stream>>>(
        x, Wl, Wr, (int*)bsum, nzero, nzb, Bt, Xbf, N);

    int nMtiles = (N + 63) / 64;         // 157
    int nMgroups = (nMtiles + 7) / 8;    // 20
    int ngemm = nMgroups * 64;           // 1280 physical gemm blocks (24 idle)
    int nscat = (E + N + 255) / 256;     // 665
    gemm_scatter_kernel<<<ngemm + nscat, 256, 0, stream>>>(
        Xbf, Bt, bl, br, ei, counts, ssrc, xlbf, xr, N, E, N, ngemm, nMtiles);

    node_kernel<<<(N + 3) / 4, 256, 0, stream>>>(
        xlbf, xr, att, bias, du, counts, ssrc, (float*)d_out, bsum, bsq, N);

    bn_apply_kernel<<<256, 256, 0, stream>>>(
        (float*)d_out, bsum, bsq, gamma, beta, N);
}

// Round 5
// 141.952 us; speedup vs baseline: 1.1807x; 1.0078x over previous
//
#include <hip/hip_runtime.h>
#include <hip/hip_bf16.h>
#include <math.h>

// N=10000, E=160000, DIN=DOUT=256. edge_index is int32 (verified R4/R5).
#define D 256
#define CAP 128           // per-node edge slots; max degree ~45 for this graph
#define NEG_SLOPE 0.2f
#define BN_EPS 1e-5f
#define NBKT 64           // BN column-sum buckets (39 atomics/address, vs R12's 2500)

typedef __attribute__((ext_vector_type(8))) short bf16x8;
typedef __attribute__((ext_vector_type(8))) unsigned short ushort8;
typedef __attribute__((ext_vector_type(4))) unsigned short ushort4v;
typedef __attribute__((ext_vector_type(4))) float f32x4;

__device__ inline unsigned short f2bf(float f) {
    union { float f; unsigned u; } v; v.f = f;
    unsigned u = v.u;
    unsigned r = u + 0x7FFFu + ((u >> 16) & 1u);   // RNE
    return (unsigned short)(r >> 16);
}
__device__ inline float bf2f(unsigned short u) {
    union { unsigned u; float f; } v; v.u = ((unsigned)u) << 16; return v.f;
}

// async global->LDS, 16B per lane. LDS dest must be linear (wave base + lane*16);
// swizzle is pre-applied to the GLOBAL layout (m173 pattern: both-sides-or-neither).
__device__ __forceinline__ void gload16(const void* g, void* l) {
    __builtin_amdgcn_global_load_lds(
        (const __attribute__((address_space(1))) unsigned int*)g,
        (__attribute__((address_space(3))) unsigned int*)l,
        16, 0, 0);
}

// ---------------------------------------------------------------------------
// prep: blocks [0,nzb) zero bsum+bsq+counts; [nzb,nzb+128) Bt transpose via
// LDS 32x32 tiles (coalesced float4 reads of W — replaces the stride-1KB
// scalar reads); [nzb+128,...) X fp32->bf16 (XOR-swizzled, zero-padded to
// Mpad rows so the GEMM staging needs no row guard).
// Swizzle: element index k ^= ((row & 7) << 3) — conflict-free ds_read_b128.
// ---------------------------------------------------------------------------
__global__ void prep_kernel(const float* __restrict__ X,
                            const float* __restrict__ Wl, const float* __restrict__ Wr,
                            int* __restrict__ zero_base, int nzero, int nzb,
                            unsigned short* __restrict__ Bt,
                            unsigned short* __restrict__ Xbf, int N) {
    int b = blockIdx.x;
    if (b < nzb) {
        int idx = b * 256 + threadIdx.x;
        if (idx < nzero) zero_base[idx] = 0;
    } else if (b < nzb + 128) {
        // 32x32 tile transpose of Wl/Wr -> Bt (bf16, swizzled)
        __shared__ float tile[32][33];
        int b2 = b - nzb;                 // 0..127
        const float* W = (b2 < 64) ? Wl : Wr;
        int nbase = (b2 < 64) ? 0 : 256;  // output row offset for Wr
        int t2 = b2 & 63;
        int ti = t2 >> 3;                 // k-tile 0..7
        int tj = t2 & 7;                  // n-tile 0..7
        int t = threadIdx.x;
        int r = t >> 3;                   // 0..31
        int c4 = (t & 7) * 4;             // 0..28
        // coalesced read: row k = ti*32+r, cols nn = tj*32+c4..+3
        float4 v = *(const float4*)(W + (size_t)(ti * 32 + r) * 256 + tj * 32 + c4);
        tile[r][c4] = v.x; tile[r][c4 + 1] = v.y;
        tile[r][c4 + 2] = v.z; tile[r][c4 + 3] = v.w;
        __syncthreads();
        // write: output row n = tj*32 + (t>>3), k-chunk k0 = ti*32 + (t&7)*4
        int nl = t >> 3;
        int n = tj * 32 + nl;
        int k0 = ti * 32 + c4;
        int sw = (n & 7) << 3;
        int ks = k0 ^ sw;                 // XOR touches bits 3-5 only; k0%4==0 safe
        ushort4v o;
        o[0] = f2bf(tile[c4][nl]);
        o[1] = f2bf(tile[c4 + 1][nl]);
        o[2] = f2bf(tile[c4 + 2][nl]);
        o[3] = f2bf(tile[c4 + 3][nl]);
        *(ushort4v*)(Bt + (size_t)(nbase + n) * 256 + ks) = o;
    } else {
        int idx = (b - nzb - 128) * 256 + threadIdx.x;   // one 16B chunk (8 elems)
        int row = idx >> 5;                        // 0..Mpad-1
        int k0 = (idx & 31) * 8;                   // element base, multiple of 8
        int ks = k0 ^ ((row & 7) << 3);            // swizzled chunk slot
        ushort8 v = {0, 0, 0, 0, 0, 0, 0, 0};
        if (row < N) {
            const float* src = X + (size_t)row * 256 + k0;
            float4 f0 = *(const float4*)(src);
            float4 f1 = *(const float4*)(src + 4);
            v[0] = f2bf(f0.x); v[1] = f2bf(f0.y);
            v[2] = f2bf(f0.z); v[3] = f2bf(f0.w);
            v[4] = f2bf(f1.x); v[5] = f2bf(f1.y);
            v[6] = f2bf(f1.z); v[7] = f2bf(f1.w);
        }
        *(ushort8*)(Xbf + (size_t)row * 256 + ks) = v;   // pad rows -> zeros
    }
}

// ---------------------------------------------------------------------------
// gemm_scatter: blocks [0,ngemm) = 64x64 MFMA GEMM tiles with XCD-affinity
// swizzle (kept from R4 — null but theoretically sound, zero cost).
// Staging is pure global_load_lds width-16 into linear LDS (swizzle baked
// into the global layout). blocks [ngemm,...) = per-dst edge slot scatter.
// ---------------------------------------------------------------------------
__global__ __launch_bounds__(256) void gemm_scatter_kernel(
    const unsigned short* __restrict__ Xbf, const unsigned short* __restrict__ Bt,
    const float* __restrict__ bl, const float* __restrict__ br,
    const int* __restrict__ ei, int* __restrict__ counts, int* __restrict__ ssrc,
    unsigned short* __restrict__ xlbf, float* __restrict__ xr,
    int M, int E, int N, int ngemm, int nMtiles)
{
    if ((int)blockIdx.x >= ngemm) {
        int e = (blockIdx.x - ngemm) * 256 + threadIdx.x;
        if (e < E + N) {
            int src, dst;
            if (e < E) { src = ei[e]; dst = ei[E + e]; }
            else       { src = dst = e - E; }          // self-loop
            int pos = atomicAdd(&counts[dst], 1);
            if (pos < CAP) ssrc[dst * CAP + pos] = src;
        }
        return;
    }

    // XCD-affinity decomposition (dispatch b -> XCD b%8)
    const int b = blockIdx.x;
    const int r = (b & 7) + 8 * (b >> 6);           // row-tile: constant b%8 across c
    const int c = (b >> 3) & 7;                     // col-tile 0..7
    if (r >= nMtiles) return;                       // guard (before any barrier)

    __shared__ __align__(16) unsigned short As[64 * 128];   // linear, swizzled content
    __shared__ __align__(16) unsigned short Bs[64 * 128];

    const int tid = threadIdx.x;
    const int wave = tid >> 6, lane = tid & 63;
    const int m_l = lane & 15, quad = lane >> 4;
    const int row0 = r * 64;
    const int n0 = c * 64;
    const int sw = (m_l & 7) << 3;                  // read-side XOR (elements)

    f32x4 acc[4] = {};

    for (int k0 = 0; k0 < 256; k0 += 128) {
        __syncthreads();
        #pragma unroll
        for (int i = 0; i < 4; i++) {
            int L = (tid + i * 256) * 16;           // LDS byte offset 0..16368
            int rr = L >> 8;                        // tile row 0..63
            int cb = L & 255;                       // byte within 128-elem half
            gload16((const char*)Xbf + (size_t)(row0 + rr) * 512 + (size_t)k0 * 2 + cb,
                    (char*)As + L);
            gload16((const char*)Bt + (size_t)(n0 + rr) * 512 + (size_t)k0 * 2 + cb,
                    (char*)Bs + L);
        }
        __syncthreads();   // compiler drains vmcnt here (m97 pattern)

        #pragma unroll
        for (int kk0 = 0; kk0 < 128; kk0 += 32) {
            int ka = (kk0 + quad * 8) ^ sw;         // swizzled element index
            bf16x8 a = *(const bf16x8*)&As[(wave * 16 + m_l) * 128 + ka];
            #pragma unroll
            for (int cc = 0; cc < 4; cc++) {
                bf16x8 bv = *(const bf16x8*)&Bs[(cc * 16 + m_l) * 128 + ka];
                acc[cc] = __builtin_amdgcn_mfma_f32_16x16x32_bf16(a, bv, acc[cc], 0, 0, 0);
            }
        }
    }

    const bool isl = (n0 < 256);
    #pragma unroll
    for (int cc = 0; cc < 4; cc++) {
        int col = n0 + cc * 16 + m_l;
        int col8 = col & 255;
        float bv = isl ? bl[col8] : br[col8];
        #pragma unroll
        for (int rr = 0; rr < 4; rr++) {
            int row = row0 + wave * 16 + quad * 4 + rr;
            if (row < M) {
                float v = acc[cc][rr] + bv;
                if (isl) xlbf[(size_t)row * 256 + col8] = f2bf(v);
                else     xr[(size_t)row * 256 + col8] = v;
            }
        }
    }
}

// ---------------------------------------------------------------------------
// node: 2500 blocks x 4 waves, ONE NODE PER WAVE. Register adjacency + shfl
// addressing. THIS ROUND: VGPR diet to lift occupancy 2->4 waves/SIMD:
//  - f0..f3 float arrays eliminated (recompute bf2f from c0..c3 at both
//    use sites — one v_lshlrev each, bit-identical)
//  - cold fallback path unified into a 64-edge chunk loop (one codegen path)
//  - du load back in the epilogue (R4 hoist was null and cost 8 live regs)
//  - __launch_bounds__(256,4) pins the allocator at 128 VGPR
// Fused bias+ReLU+dropout + BN bucket stats (64 buckets — R12 lesson).
// ---------------------------------------------------------------------------
__device__ inline float dot8leakyc(ushort8 c, float4 bA, float4 bB,
                                   float4 aA, float4 aB) {
    float h, s = 0.f;
    h = bf2f(c[0]) + bA.x; h = (h > 0.f) ? h : NEG_SLOPE * h; s += h * aA.x;
    h = bf2f(c[1]) + bA.y; h = (h > 0.f) ? h : NEG_SLOPE * h; s += h * aA.y;
    h = bf2f(c[2]) + bA.z; h = (h > 0.f) ? h : NEG_SLOPE * h; s += h * aA.z;
    h = bf2f(c[3]) + bA.w; h = (h > 0.f) ? h : NEG_SLOPE * h; s += h * aA.w;
    h = bf2f(c[4]) + bB.x; h = (h > 0.f) ? h : NEG_SLOPE * h; s += h * aB.x;
    h = bf2f(c[5]) + bB.y; h = (h > 0.f) ? h : NEG_SLOPE * h; s += h * aB.y;
    h = bf2f(c[6]) + bB.z; h = (h > 0.f) ? h : NEG_SLOPE * h; s += h * aB.z;
    h = bf2f(c[7]) + bB.w; h = (h > 0.f) ? h : NEG_SLOPE * h; s += h * aB.w;
    return s;
}

__global__ __launch_bounds__(256, 4) void node_kernel(
    const unsigned short* __restrict__ xlbf, const float* __restrict__ xr,
    const float* __restrict__ att, const float* __restrict__ bias,
    const float* __restrict__ du, const int* __restrict__ counts,
    const int* __restrict__ ssrc, float* __restrict__ out,
    float* __restrict__ bsum, float* __restrict__ bsq, int N)
{
    __shared__ float ls[4][256];

    const int wave = threadIdx.x >> 6, lane = threadIdx.x & 63;
    const int i = blockIdx.x * 4 + wave;
    const bool valid = (i < N);
    const int hl = lane & 31;
    const int sid = lane >> 5;                  // stream 0 or 1

    int cnt = valid ? counts[i] : 0;
    if (cnt > CAP) cnt = CAP;
    const int start = i * CAP, end = start + cnt;

    const float4 attA = ((const float4*)att)[hl * 2];
    const float4 attB = ((const float4*)att)[hl * 2 + 1];
    const float4 zf4 = {0.f, 0.f, 0.f, 0.f};
    const float4 bA = valid ? ((const float4*)(xr + (size_t)i * D))[hl * 2] : zf4;
    const float4 bB = valid ? ((const float4*)(xr + (size_t)i * D))[hl * 2 + 1] : zf4;

    float m = -INFINITY, lsum = 0.f;
    float acc[8] = {0.f, 0.f, 0.f, 0.f, 0.f, 0.f, 0.f, 0.f};
    const ushort8 z8 = {0, 0, 0, 0, 0, 0, 0, 0};
    const unsigned short* xb = xlbf + hl * 8;

    // 64-edge chunks: one unified path (cnt<=64 -> single chunk, identical
    // to the old fast path; cnt in (64,128] handled by a second chunk).
    for (int cs = start; cs < end; cs += 64) {
        const int cend = (end < cs + 64) ? end : cs + 64;
        int srcv = ssrc[cs + lane];             // in-bounds: cs+lane < start+CAP
        int e = cs + sid;                       // stream edges: e, e+2, e+4, ...

        ushort8 p0, p1, p2, p3;
        {
            int a0 = __shfl(srcv, sid);
            int a1 = __shfl(srcv, sid + 2);
            int a2 = __shfl(srcv, sid + 4);
            int a3 = __shfl(srcv, sid + 6);
            p0 = (e     < cend) ? *(const ushort8*)(xb + (size_t)a0 * D) : z8;
            p1 = (e + 2 < cend) ? *(const ushort8*)(xb + (size_t)a1 * D) : z8;
            p2 = (e + 4 < cend) ? *(const ushort8*)(xb + (size_t)a2 * D) : z8;
            p3 = (e + 6 < cend) ? *(const ushort8*)(xb + (size_t)a3 * D) : z8;
        }

        while (e < cend) {
            ushort8 c0 = p0, c1 = p1, c2 = p2, c3 = p3;
            bool v1 = (e + 2 < cend), v2 = (e + 4 < cend), v3 = (e + 6 < cend);
            int en = e + 8;
            {
                int on = (en - cs) & 63;        // &63: shfl src safe when unused
                int a0 = __shfl(srcv, on);
                int a1 = __shfl(srcv, on + 2);
                int a2 = __shfl(srcv, on + 4);
                int a3 = __shfl(srcv, on + 6);
                p0 = (en     < cend) ? *(const ushort8*)(xb + (size_t)a0 * D) : z8;
                p1 = (en + 2 < cend) ? *(const ushort8*)(xb + (size_t)a1 * D) : z8;
                p2 = (en + 4 < cend) ? *(const ushort8*)(xb + (size_t)a2 * D) : z8;
                p3 = (en + 6 < cend) ? *(const ushort8*)(xb + (size_t)a3 * D) : z8;
            }

            float s0 = dot8leakyc(c0, bA, bB, attA, attB);
            float s1 = dot8leakyc(c1, bA, bB, attA, attB);
            float s2 = dot8leakyc(c2, bA, bB, attA, attB);
            float s3 = dot8leakyc(c3, bA, bB, attA, attB);

            #pragma unroll
            for (int off = 1; off < 32; off <<= 1) {    // 5-step, within half-wave
                s0 += __shfl_xor(s0, off);
                s1 += __shfl_xor(s1, off);
                s2 += __shfl_xor(s2, off);
                s3 += __shfl_xor(s3, off);
            }
            if (!v1) s1 = -INFINITY;
            if (!v2) s2 = -INFINITY;
            if (!v3) s3 = -INFINITY;

            float mnew = fmaxf(fmaxf(m, fmaxf(s0, s1)), fmaxf(s2, s3));
            float sc = __expf(m - mnew);                 // exp(-inf-finite)=0, safe
            float e0e = __expf(s0 - mnew);
            float e1e = __expf(s1 - mnew);
            float e2e = __expf(s2 - mnew);
            float e3e = __expf(s3 - mnew);
            lsum = lsum * sc + e0e + e1e + e2e + e3e;
            #pragma unroll
            for (int k = 0; k < 8; k++) {
                acc[k] = acc[k] * sc + e0e * bf2f(c0[k]) + e1e * bf2f(c1[k])
                                     + e2e * bf2f(c2[k]) + e3e * bf2f(c3[k]);
            }
            m = mnew;
            e = en;
        }
    }

    // combine the two half-wave streams (guard -inf - -inf = nan; stream 1 may
    // be empty for degree-1 nodes, stream 0 always has the self-loop)
    {
        float mO = __shfl_xor(m, 32);
        float lO = __shfl_xor(lsum, 32);
        float accO[8];
        #pragma unroll
        for (int k = 0; k < 8; k++) accO[k] = __shfl_xor(acc[k], 32);
        float mn = fmaxf(m, mO);
        float wS = (m  == -INFINITY) ? 0.f : __expf(m - mn);
        float wO = (mO == -INFINITY) ? 0.f : __expf(mO - mn);
        lsum = lsum * wS + lO * wO;
        #pragma unroll
        for (int k = 0; k < 8; k++) acc[k] = acc[k] * wS + accO[k] * wO;
    }

    // epilogue: bias+ReLU+dropout, store, and stage values for BN stats
    float ov[8];
    if (lane < 32) {
        if (valid) {
            float inv = 1.f / lsum;
            float4 biA = ((const float4*)bias)[hl * 2];
            float4 biB = ((const float4*)bias)[hl * 2 + 1];
            float4 uA = ((const float4*)(du + (size_t)i * D))[hl * 2];
            float4 uB = ((const float4*)(du + (size_t)i * D))[hl * 2 + 1];
            float4 oA, oB;
            oA.x = fmaxf(acc[0] * inv + biA.x, 0.f); oA.x = (uA.x >= 0.5f) ? 2.f * oA.x : 0.f;
            oA.y = fmaxf(acc[1] * inv + biA.y, 0.f); oA.y = (uA.y >= 0.5f) ? 2.f * oA.y : 0.f;
            oA.z = fmaxf(acc[2] * inv + biA.z, 0.f); oA.z = (uA.z >= 0.5f) ? 2.f * oA.z : 0.f;
            oA.w = fmaxf(acc[3] * inv + biA.w, 0.f); oA.w = (uA.w >= 0.5f) ? 2.f * oA.w : 0.f;
            oB.x = fmaxf(acc[4] * inv + biB.x, 0.f); oB.x = (uB.x >= 0.5f) ? 2.f * oB.x : 0.f;
            oB.y = fmaxf(acc[5] * inv + biB.y, 0.f); oB.y = (uB.y >= 0.5f) ? 2.f * oB.y : 0.f;
            oB.z = fmaxf(acc[6] * inv + biB.z, 0.f); oB.z = (uB.z >= 0.5f) ? 2.f * oB.z : 0.f;
            oB.w = fmaxf(acc[7] * inv + biB.w, 0.f); oB.w = (uB.w >= 0.5f) ? 2.f * oB.w : 0.f;
            ((float4*)(out + (size_t)i * D))[hl * 2] = oA;
            ((float4*)(out + (size_t)i * D))[hl * 2 + 1] = oB;
            ov[0] = oA.x; ov[1] = oA.y; ov[2] = oA.z; ov[3] = oA.w;
            ov[4] = oB.x; ov[5] = oB.y; ov[6] = oB.z; ov[7] = oB.w;
        } else {
            #pragma unroll
            for (int k = 0; k < 8; k++) ov[k] = 0.f;
        }
        #pragma unroll
        for (int k = 0; k < 8; k++) ls[wave][hl * 8 + k] = ov[k];
    }
    __syncthreads();

    // per-block column reduction over the 4 rows, one atomic pair per column
    {
        int t = threadIdx.x;
        float s = 0.f, s2 = 0.f;
        #pragma unroll
        for (int w = 0; w < 4; w++) {
            float v = ls[w][t];
            s += v; s2 += v * v;
        }
        int bkt = (blockIdx.x & (NBKT - 1)) * 256 + t;
        atomicAdd(&bsum[bkt], s);
        atomicAdd(&bsq[bkt], s2);
    }
}

// ---------------------------------------------------------------------------
// bn_apply: 256 blocks. Prologue reduces the 64 buckets (coalesced, LDS-cached
// scale/shift), then one FMA per element over out in place.
// ---------------------------------------------------------------------------
__global__ __launch_bounds__(256) void bn_apply_kernel(
    float* __restrict__ out,
    const float* __restrict__ bsum, const float* __restrict__ bsq,
    const float* __restrict__ gamma, const float* __restrict__ beta, int N)
{
    __shared__ float scaleL[256], shiftL[256];
    const int t = threadIdx.x;
    float s = 0.f, s2 = 0.f;
    #pragma unroll 8
    for (int b = 0; b < NBKT; b++) {
        s += bsum[b * 256 + t];
        s2 += bsq[b * 256 + t];
    }
    float invN = 1.f / (float)N;
    float mean = s * invN;
    float var = s2 * invN - mean * mean;
    float rs = rsqrtf(var + BN_EPS);
    float sc = gamma[t] * rs;
    scaleL[t] = sc;
    shiftL[t] = beta[t] - mean * sc;
    __syncthreads();

    const int c4 = t & 63;                       // float4 slot within row
    float4 scv, shv;
    scv.x = scaleL[c4 * 4];     shv.x = shiftL[c4 * 4];
    scv.y = scaleL[c4 * 4 + 1]; shv.y = shiftL[c4 * 4 + 1];
    scv.z = scaleL[c4 * 4 + 2]; shv.z = shiftL[c4 * 4 + 2];
    scv.w = scaleL[c4 * 4 + 3]; shv.w = shiftL[c4 * 4 + 3];

    for (int row = blockIdx.x * 4 + (t >> 6); row < N; row += gridDim.x * 4) {
        float4 v = ((float4*)(out + (size_t)row * D))[c4];
        v.x = v.x * scv.x + shv.x;
        v.y = v.y * scv.y + shv.y;
        v.z = v.z * scv.z + shv.z;
        v.w = v.w * scv.w + shv.w;
        ((float4*)(out + (size_t)row * D))[c4] = v;
    }
}

// ---------------------------------------------------------------------------
extern "C" void kernel_launch(void* const* d_in, const int* in_sizes, int n_in,
                              void* d_out, int out_size, void* d_ws, size_t ws_size,
                              hipStream_t stream) {
    const float* x     = (const float*)d_in[0];
    const int*   ei    = (const int*)d_in[1];
    const float* Wl    = (const float*)d_in[2];
    const float* bl    = (const float*)d_in[3];
    const float* Wr    = (const float*)d_in[4];
    const float* br    = (const float*)d_in[5];
    const float* att   = (const float*)d_in[6];
    const float* bias  = (const float*)d_in[7];
    const float* gamma = (const float*)d_in[8];
    const float* beta  = (const float*)d_in[9];
    const float* du    = (const float*)d_in[10];

    const int N = in_sizes[0] / D;       // 10000
    const int E = in_sizes[1] / 2;       // 160000
    const int Mpad = (N + 63) & ~63;     // 10048: zero-padded rows for guard-free staging

    // workspace layout (4-byte word units)
    int* ws = (int*)d_ws;
    size_t off = 0;
    float* xr       = (float*)(ws + off); off += (size_t)N * D;
    unsigned short* xlbf = (unsigned short*)(ws + off); off += (size_t)N * D / 2;
    unsigned short* Xbf  = (unsigned short*)(ws + off); off += (size_t)Mpad * D / 2;
    unsigned short* Bt   = (unsigned short*)(ws + off); off += 512 * 256 / 2;
    int*   ssrc     = ws + off;           off += (size_t)N * CAP;
    // contiguous zeroed region (zeroed by prep_kernel blocks [0,nzb)):
    float* bsum     = (float*)(ws + off); off += NBKT * 256;
    float* bsq      = (float*)(ws + off); off += NBKT * 256;
    int*   counts   = ws + off;           off += N;
    int nzero = 2 * NBKT * 256 + N;      // 42768 words
    int nzb = (nzero + 255) / 256;       // 168 zero blocks

    int nconv = (Mpad * 32) / 256;       // 1256 blocks, 8 elems/thread
    prep_kernel<<<nzb + 128 + nconv, 256, 0, stream>>>(
        x, Wl, Wr, (int*)bsum, nzero, nzb, Bt, Xbf, N);

    int nMtiles = (N + 63) / 64;         // 157
    int nMgroups = (nMtiles + 7) / 8;    // 20
    int ngemm = nMgroups * 64;           // 1280 physical gemm blocks (24 idle)
    int nscat = (E + N + 255) / 256;     // 665
    gemm_scatter_kernel<<<ngemm + nscat, 256, 0, stream>>>(
        Xbf, Bt, bl, br, ei, counts, ssrc, xlbf, xr, N, E, N, ngemm, nMtiles);

    node_kernel<<<(N + 3) / 4, 256, 0, stream>>>(
        xlbf, xr, att, bias, du, counts, ssrc, (float*)d_out, bsum, bsq, N);

    bn_apply_kernel<<<256, 256, 0, stream>>>(
        (float*)d_out, bsum, bsq, gamma, beta, N);
}